// Round 5
// baseline (1320.735 us; speedup 1.0000x reference)
//
#include <hip/hip_runtime.h>
#include <cstdint>
#include <math.h>

// XLA CPU (no fast-math) emits unfused mul/add for all HLO-level elementwise ops.
#pragma clang fp contract(off)

#define DEV __device__ __forceinline__

// ---------------------------------------------------------------- threefry2x32
struct U2 { unsigned a, b; };

DEV unsigned rotl32(unsigned v, int d) { return (v << d) | (v >> (32 - d)); }

DEV U2 tf2(unsigned k0, unsigned k1, unsigned x0, unsigned x1) {
  unsigned ks2 = k0 ^ k1 ^ 0x1BD11BDAu;
  x0 += k0; x1 += k1;
#define TFR(r) { x0 += x1; x1 = rotl32(x1, r); x1 ^= x0; }
  TFR(13) TFR(15) TFR(26) TFR(6)
  x0 += k1; x1 += ks2 + 1u;
  TFR(17) TFR(29) TFR(16) TFR(24)
  x0 += ks2; x1 += k0 + 2u;
  TFR(13) TFR(15) TFR(26) TFR(6)
  x0 += k0; x1 += k1 + 3u;
  TFR(17) TFR(29) TFR(16) TFR(24)
  x0 += k1; x1 += ks2 + 4u;
  TFR(13) TFR(15) TFR(26) TFR(6)
  x0 += ks2; x1 += k0 + 5u;
#undef TFR
  U2 r; r.a = x0; r.b = x1; return r;
}

DEV unsigned rbits(unsigned k0, unsigned k1, unsigned idx) {
  U2 o = tf2(k0, k1, 0u, idx);
  return o.a ^ o.b;
}

DEV float u01(unsigned bits) {
  return __uint_as_float((bits >> 9) | 0x3F800000u) - 1.0f;
}

// ---------------------------------------------------------------- XLA CPU math
DEV float xla_exp(float xi) {
  float x = fminf(fmaxf(xi, -88.3762626647949f), 88.3762626647950f);
  float fx = floorf(x * 1.44269504088896341f + 0.5f);
  float tmp = 0.693359375f * fx;
  float z = -2.12194440e-4f * fx;
  x = x - tmp;
  x = x - z;
  z = x * x;
  float y = 1.9875691500e-4f * x + 1.3981999507e-3f;
  y = y * x + 8.3334519073e-3f;
  y = y * x + 4.1665795894e-2f;
  y = y * x + 1.6666665459e-1f;
  y = y * x + 5.0000001201e-1f;
  y = y * z + x;
  y = y + 1.0f;
  int n = (int)fx;
  float two_n = __uint_as_float((unsigned)(n + 127) << 23);
  return fmaxf(y * two_n, xi);
}

DEV float xla_log(float xi) {
  float xc = fmaxf(xi, 1.17549435082228751e-38f);
  unsigned bits = __float_as_uint(xc);
  float e = (float)((int)(bits >> 23) - 126);
  float m = __uint_as_float((bits & 0x007FFFFFu) | 0x3F000000u);
  bool msk = m < 0.707106781186547524f;
  float tmp = msk ? m : 0.0f;
  float em  = msk ? 1.0f : 0.0f;
  m = m - 1.0f;
  e = e - em;
  m = m + tmp;
  float z  = m * m;
  float x3 = z * m;
  float y0 = 7.0376836292e-2f  * m + -1.1514610310e-1f;
  float y1 = -1.2420140846e-1f * m + 1.4249322787e-1f;
  float y2 = 2.0000714765e-1f  * m + -2.4999993993e-1f;
  y0 = y0 * m + 1.1676998740e-1f;
  y1 = y1 * m + -1.6668057665e-1f;
  y2 = y2 * m + 3.3333331174e-1f;
  y0 = y0 * x3 + y1;
  y0 = y0 * x3 + y2;
  y0 = y0 * x3;
  y0 = -2.12194440e-4f * e + y0;
  y0 = y0 - 0.5f * z;
  float r = m + y0;
  r = 0.693359375f * e + r;
  if (!(xi > 0.0f)) r = (xi == 0.0f) ? -__builtin_inff() : __builtin_nanf("");
  if (xi == __builtin_inff()) r = __builtin_inff();
  return r;
}

DEV float xla_tanh(float x) {
  float xc = fminf(fmaxf(x, -9.0f), 9.0f);
  float x2 = xc * xc;
  float p = x2 * -2.76076847742355e-16f + 2.00018790482477e-13f;
  p = p * x2 + -8.60467152213735e-11f;
  p = p * x2 + 5.12229709037114e-08f;
  p = p * x2 + 1.48572235717979e-05f;
  p = p * x2 + 6.37261928875436e-04f;
  p = p * x2 + 4.89352455891786e-03f;
  p = xc * p;
  float q = x2 * 1.19825839466702e-06f + 1.18534705686654e-04f;
  q = q * x2 + 2.26843463243900e-03f;
  q = q * x2 + 4.89352518554385e-03f;
  float r = p / q;
  return (fabsf(x) < 0.0004f) ? x : r;
}

DEV float sqrt_cr(float x) { return (float)sqrt((double)x); }

DEV float xla_log1p(float x) {
  float fl = xla_log(x + 1.0f);
  float fs = ((-0.5f) * x + 1.0f) * x;
  return (fabsf(x) < 1e-4f) ? fs : fl;
}

DEV float softplus_ref(float x) {
  float amax = fmaxf(x, 0.0f);
  return amax + xla_log1p(xla_exp(-fabsf(x)));
}

DEV float xla_erfinv(float x) {
  float w = -xla_log1p(-(x * x));
  bool lt = w < 5.0f;
  float wa = lt ? (w - 2.5f) : (sqrt_cr(w) - 3.0f);
  float p;
  if (lt) {
    p = 2.81022636e-08f;
    p = p * wa + 3.43273939e-07f;
    p = p * wa + -3.5233877e-06f;
    p = p * wa + -4.39150654e-06f;
    p = p * wa + 0.00021858087f;
    p = p * wa + -0.00125372503f;
    p = p * wa + -0.00417768164f;
    p = p * wa + 0.246640727f;
    p = p * wa + 1.50140941f;
  } else {
    p = -0.000200214257f;
    p = p * wa + 0.000100950558f;
    p = p * wa + 0.00134934322f;
    p = p * wa + -0.00367342844f;
    p = p * wa + 0.00573950773f;
    p = p * wa + -0.0076224613f;
    p = p * wa + 0.00943887047f;
    p = p * wa + 1.00167406f;
    p = p * wa + 2.83297682f;
  }
  return p * x;
}

DEV float powm(float x) {
  const double e = (double)((float)(-1.0 / 1.2));
  return (float)pow((double)x, e);
}

// ---------------------------------------------------------------- constants
#define SIG2F  0.0025000000000000005f
#define RATE1F 13.207443270509278f
#define LO_N  -0.99999994039535522f
#define SQRT2F 1.4142135623730951f
#define Tn 64

// ---------------------------------------------------------------- atomics
#define AGENT __HIP_MEMORY_SCOPE_AGENT
DEV void spin_ge(const unsigned* p, unsigned target) {
  while (__hip_atomic_load(p, __ATOMIC_RELAXED, AGENT) < target)
    __builtin_amdgcn_s_sleep(2);
  __builtin_amdgcn_fence(__ATOMIC_ACQUIRE, "agent");
}
DEV void release_add(unsigned* p) {
  __builtin_amdgcn_fence(__ATOMIC_RELEASE, "agent");
  __hip_atomic_fetch_add(p, 1u, __ATOMIC_RELAXED, AGENT);
}

// ================================================================ FAT path
// ws layout (float / uint indices)
#define F_A      0          // 2048
#define F_B      2048       // 2048
#define F_DS     4096       // 32
#define F_KEYS   4128       // 512 u
#define F_KA     4640       // 1024 u
#define F_KP     5664       // 1024 u
#define F_SUB    6688       // 2176 u
#define F_CNT    8864       // 65 u (cnt[64], initFlag at +64)
#define F_SCALED 16384      // 4194304
#define F_QUAD   4210688    // 4194304
#define F_RP2    8404992    // 8388608
#define F_SQ     16793600   // 8388608
#define F_U2     25182208   // 8388608
#define F_Z      33570816   // 1048576
#define F_LK     34619392   // 1114112
#define F_END    35733504
#define NPROD 224
#define UNITS_PER_SLAB 214016   // 65536 tilt + 131072 cand + 16384 z + 1024 lk
#define CHUNK 956               // ceil(214016/224)

__global__ void __launch_bounds__(1024) fat_kernel(
    const float* __restrict__ state_init, const float* __restrict__ tseq,
    const float* __restrict__ gW1, const float* __restrict__ gb1,
    const float* __restrict__ gW2, const float* __restrict__ gb2,
    const float* __restrict__ gW3, const float* __restrict__ gb3,
    const float* __restrict__ diff_log,
    const float* __restrict__ pW1, const float* __restrict__ pb1,
    const float* __restrict__ pW2, const float* __restrict__ pb2,
    const float* __restrict__ pW3, const float* __restrict__ pb3,
    float* ws, float* __restrict__ out) {
  unsigned* wsu = (unsigned*)ws;
  unsigned* cnt = &wsu[F_CNT];
  unsigned* initFlag = &wsu[F_CNT + 64];
  const int bid = blockIdx.x;
  const int tid = threadIdx.x;

  __shared__ float sW1[33 * 64], sB1[64], sW2[64 * 64], sB2[64], sW3[64 * 32], sB3[32];
  __shared__ float sTseq[64];
  __shared__ float sX[32], sK1[32], sA[32], sMb[32], sDrift[32], sDs[32];
  __shared__ int   sNj[32];
  __shared__ float sH1[64], sH2[64];
  __shared__ float sTilt[32 * 65];
  __shared__ float sSel[4096];     // sign = accept flag, |v| = rp2
  __shared__ float sCond[512];
  __shared__ unsigned sChainK[128];

  if (bid >= 32) {
    // ============================================ producer / init role
    const int pid = bid - 32;
    if (pid == 0) {
      // ---- INIT: key tables
      if (tid == 0) {
        unsigned k0 = 0u, k1 = 42u;   // jax.random.key(42)
        for (int i = 0; i < 64; ++i) {
          sChainK[i * 2] = k0; sChainK[i * 2 + 1] = k1;
          U2 c0 = tf2(k0, k1, 0u, 0u);
          k0 = c0.a; k1 = c0.b;
        }
      }
      __syncthreads();
      if (tid < 64) {
        unsigned k0 = sChainK[tid * 2], k1 = sChainK[tid * 2 + 1];
        U2 c1 = tf2(k0, k1, 0u, 1u);  // k_stab
        U2 c2 = tf2(k0, k1, 0u, 2u);  // k_pois
        U2 c3 = tf2(k0, k1, 0u, 3u);  // k_rej
        U2 c4 = tf2(k0, k1, 0u, 4u);  // k_gauss
        wsu[F_KEYS + tid * 8 + 0] = c1.a; wsu[F_KEYS + tid * 8 + 1] = c1.b;
        wsu[F_KEYS + tid * 8 + 2] = c2.a; wsu[F_KEYS + tid * 8 + 3] = c2.b;
        wsu[F_KEYS + tid * 8 + 4] = c3.a; wsu[F_KEYS + tid * 8 + 5] = c3.b;
        wsu[F_KEYS + tid * 8 + 6] = c4.a; wsu[F_KEYS + tid * 8 + 7] = c4.b;
        unsigned a0 = c3.a, a1 = c3.b;
        for (int a = 0; a < 8; ++a) {
          U2 kp = tf2(a0, a1, 0u, 1u);
          U2 ka = tf2(a0, a1, 0u, 2u);
          U2 nx = tf2(a0, a1, 0u, 0u);
          wsu[F_KP + (tid * 8 + a) * 2 + 0] = kp.a; wsu[F_KP + (tid * 8 + a) * 2 + 1] = kp.b;
          wsu[F_KA + (tid * 8 + a) * 2 + 0] = ka.a; wsu[F_KA + (tid * 8 + a) * 2 + 1] = ka.b;
          a0 = nx.a; a1 = nx.b;
        }
        unsigned r0 = c2.a, r1 = c2.b;
        for (int k = 0; k < 17; ++k) {
          U2 sub = tf2(r0, r1, 0u, 1u);
          U2 nx  = tf2(r0, r1, 0u, 0u);
          wsu[F_SUB + (tid * 17 + k) * 2 + 0] = sub.a; wsu[F_SUB + (tid * 17 + k) * 2 + 1] = sub.b;
          r0 = nx.a; r1 = nx.b;
        }
      }
      __syncthreads();
      // ---- INIT: phi MLP (scrA = sSel, scrB = sW2)
      for (int j = tid; j < 4096; j += 1024) {
        int tt = j >> 6, w_ = j & 63;
        sSel[j] = xla_tanh(tseq[tt] * pW1[w_] + pb1[w_]);
      }
      __syncthreads();
      for (int j = tid; j < 4096; j += 1024) {
        int tt = j >> 6, w_ = j & 63;
        float acc = 0.0f;
        for (int k = 0; k < 64; ++k) acc = fmaf(sSel[tt * 64 + k], pW2[k * 64 + w_], acc);
        sW2[j] = xla_tanh(acc + pb2[w_]);
      }
      __syncthreads();
      for (int j = tid; j < 4096; j += 1024) {
        int tt = j >> 6, o = j & 63;
        float acc = 0.0f;
        for (int k = 0; k < 64; ++k) acc = fmaf(sW2[tt * 64 + k], pW3[k * 64 + o], acc);
        acc = acc + pb3[o];
        if (o < 32) ws[F_A + tt * 32 + o] = -softplus_ref(acc);
        else        ws[F_B + tt * 32 + (o - 32)] = acc;
      }
      if (tid < 32) ws[F_DS + tid] = softplus_ref(diff_log[tid]);
      __syncthreads();
      if (tid == 0) {
        __builtin_amdgcn_fence(__ATOMIC_RELEASE, "agent");
        __hip_atomic_store(initFlag, 1u, __ATOMIC_RELAXED, AGENT);
      }
    }
    if (tid == 0) spin_ge(initFlag, 1u);
    __syncthreads();

    const int u0 = pid * CHUNK;
    const int u1 = (u0 + CHUNK < UNITS_PER_SLAB) ? (u0 + CHUNK) : UNITS_PER_SLAB;
    for (int t = 0; t < Tn; ++t) {
      int u = u0 + tid;
      if (u < u1) {
        if (u < 65536) {
          int b_ = u >> 11, e = u & 2047, d = e & 31;
          unsigned k0 = wsu[F_KEYS + t * 8 + 0], k1 = wsu[F_KEYS + t * 8 + 1];
          float uu = u01(rbits(k0, k1, (unsigned)(b_ * 2048 + e)));
          float raw = 0.1f * powm(1.0f - uu);
          float scaled = ws[F_DS + d] * raw;
          float A = ws[F_A + t * 32 + d];
          ws[F_SCALED + t * 65536 + u] = scaled;
          ws[F_QUAD   + t * 65536 + u] = A * (scaled * scaled);
        } else if (u < 196608) {
          int i = u - 65536;
          int b_ = i >> 12, jd = (i >> 3) & 511, a = i & 7, d = jd & 31;
          unsigned p0 = wsu[F_KP + (t * 8 + a) * 2], p1 = wsu[F_KP + (t * 8 + a) * 2 + 1];
          float rp = 0.1f * powm(1.0f - u01(rbits(p0, p1, (unsigned)(b_ * 512 + jd))));
          float rp2 = rp * rp;
          float A = ws[F_A + t * 32 + d];
          float den = fmaxf(1.0f - ((2.0f * A) * rp2) * SIG2F, 1e-6f);
          unsigned a0 = wsu[F_KA + (t * 8 + a) * 2], a1 = wsu[F_KA + (t * 8 + a) * 2 + 1];
          ws[F_RP2 + t * 131072 + i] = rp2;
          ws[F_SQ  + t * 131072 + i] = sqrt_cr(den);
          ws[F_U2  + t * 131072 + i] = u01(rbits(a0, a1, (unsigned)(b_ * 512 + jd)));
        } else if (u < 212992) {
          int i = u - 196608;
          int b_ = i >> 9, jd = i & 511;
          unsigned g0 = wsu[F_KEYS + t * 8 + 6], g1 = wsu[F_KEYS + t * 8 + 7];
          float fz = u01(rbits(g0, g1, (unsigned)(b_ * 512 + jd)));
          float un = fmaxf(LO_N, fz * 2.0f + LO_N);
          ws[F_Z + t * 16384 + i] = SQRT2F * xla_erfinv(un);
        } else {
          int i = u - 212992;
          int b_ = i >> 5, d = i & 31;
          float L = 0.0f;
          for (int k = 0; k < 17; ++k) {
            unsigned s0 = wsu[F_SUB + (t * 17 + k) * 2], s1 = wsu[F_SUB + (t * 17 + k) * 2 + 1];
            L = L + xla_log(u01(rbits(s0, s1, (unsigned)(b_ * 32 + d))));
            ws[F_LK + ((t * 32 + b_) * 17 + k) * 32 + d] = L;
          }
        }
      }
      __syncthreads();
      if (tid == 0) release_add(&cnt[t]);
    }
    return;
  }

  // ============================================ sim role (blocks 0-31)
  const int b = bid;
  for (int i = tid; i < 33 * 64; i += 1024) sW1[i] = gW1[i];
  for (int i = tid; i < 64 * 64; i += 1024) sW2[i] = gW2[i];
  for (int i = tid; i < 64 * 32; i += 1024) sW3[i] = gW3[i];
  if (tid < 64) { sB1[tid] = gb1[tid]; sB2[tid] = gb2[tid]; sTseq[tid] = tseq[tid]; }
  if (tid < 32) sB3[tid] = gb3[tid];
  if (tid == 0) spin_ge(initFlag, 1u);
  __syncthreads();
  if (tid < 32) {
    sDs[tid] = ws[F_DS + tid];
    float X0 = state_init[b * 32 + tid];
    sX[tid] = X0;
    float A = ws[F_A + tid], Bv = ws[F_B + tid];
    sA[tid] = A;
    float K1 = (2.0f * A) * X0 + Bv;
    sK1[tid] = K1;
    sMb[tid] = xla_exp((-(K1 * K1)) / (4.0f * A));
  }
  if (tid == 0) spin_ge(&cnt[0], NPROD);
  __syncthreads();

  // prefetch step 0
  const int zi = tid & 511;
  float cSc0, cSc1, cSc2, cQd0, cQd1, cQd2, cRp2[4], cSq[4], cU2[4], cZ;
  {
    int tb = b;  // (0*32+b)
    cSc0 = ws[F_SCALED + tb * 2048 + tid];
    cQd0 = ws[F_QUAD + tb * 2048 + tid];
    cSc1 = (tid < 960) ? ws[F_SCALED + tb * 2048 + 960 + tid] : 0.0f;
    cQd1 = (tid < 960) ? ws[F_QUAD + tb * 2048 + 960 + tid] : 0.0f;
    cSc2 = (tid < 128) ? ws[F_SCALED + tb * 2048 + 1920 + tid] : 0.0f;
    cQd2 = (tid < 128) ? ws[F_QUAD + tb * 2048 + 1920 + tid] : 0.0f;
#pragma unroll
    for (int q = 0; q < 4; ++q) {
      cRp2[q] = ws[F_RP2 + tb * 4096 + tid + q * 1024];
      cSq[q]  = ws[F_SQ + tb * 4096 + tid + q * 1024];
      cU2[q]  = ws[F_U2 + tb * 4096 + tid + q * 1024];
    }
    cZ = ws[F_Z + tb * 512 + zi];
  }
  __syncthreads();

  float past_t = sTseq[0];
  for (int ti = 0; ti < Tn; ++ti) {
    float t = sTseq[ti];
    float dt = t - past_t;

    // ---- P1: waves 0-14 tilt; wave 15 drift MLP (same-wave LDS)
    if (tid >= 960) {
      int l = tid - 960;
      float acc = 0.0f;
      acc = fmaf(t, sW1[l], acc);
      for (int k = 1; k < 33; ++k) acc = fmaf(sX[k - 1], sW1[k * 64 + l], acc);
      acc = acc + sB1[l];
      sH1[l] = xla_tanh(acc);
      float acc2 = 0.0f;
      for (int k = 0; k < 64; ++k) acc2 = fmaf(sH1[k], sW2[k * 64 + l], acc2);
      acc2 = acc2 + sB2[l];
      sH2[l] = xla_tanh(acc2);
      if (l < 32) {
        float a3 = 0.0f;
        for (int k = 0; k < 64; ++k) a3 = fmaf(sH2[k], sW3[k * 32 + l], a3);
        sDrift[l] = a3 + sB3[l];
      }
    } else {
      {
        int d = tid & 31;
        float lin = sK1[d] * cSc0;
        float lh = 80.0f * xla_tanh((cQd0 + lin) / 80.0f);
        float nh = 80.0f * xla_tanh((cQd0 - lin) / 80.0f);
        sTilt[d * 65 + (tid >> 5)] = xla_exp(lh) + xla_exp(nh);
      }
      {
        int e = tid + 960, d = e & 31;
        float lin = sK1[d] * cSc1;
        float lh = 80.0f * xla_tanh((cQd1 + lin) / 80.0f);
        float nh = 80.0f * xla_tanh((cQd1 - lin) / 80.0f);
        sTilt[d * 65 + (e >> 5)] = xla_exp(lh) + xla_exp(nh);
      }
      if (tid < 128) {
        int e = 1920 + tid, d = e & 31;
        float lin = sK1[d] * cSc2;
        float lh = 80.0f * xla_tanh((cQd2 + lin) / 80.0f);
        float nh = 80.0f * xla_tanh((cQd2 - lin) / 80.0f);
        sTilt[d * 65 + (e >> 5)] = xla_exp(lh) + xla_exp(nh);
      }
    }
    __syncthreads();

    // ---- P2: ranks 59/60 via 5 max-extractions (2 d's per wave)
    {
      int wv = tid >> 6, lane = tid & 63;
      float vo0 = sTilt[wv * 65 + lane];
      float vo1 = sTilt[(wv + 16) * 65 + lane];
      float w0 = vo0, w1 = vo1;
      float s0_59 = 0.0f, s0_60 = 0.0f, s1_59 = 0.0f, s1_60 = 0.0f;
#pragma unroll
      for (int it = 0; it < 5; ++it) {
        float m0 = w0, m1 = w1;
#pragma unroll
        for (int j = 1; j < 64; j <<= 1) {
          m0 = fmaxf(m0, __shfl_xor(m0, j, 64));
          m1 = fmaxf(m1, __shfl_xor(m1, j, 64));
        }
        if (it == 3) { s0_60 = m0; s1_60 = m1; }
        if (it == 4) { s0_59 = m0; s1_59 = m1; }
        if (it < 4) {
          unsigned long long b0 = __ballot(w0 == m0);
          unsigned long long b1 = __ballot(w1 == m1);
          int l0 = __ffsll(b0) - 1;
          int l1 = __ffsll(b1) - 1;
          if (lane == l0) w0 = -1.0f;
          if (lane == l1) w1 = -1.0f;
        }
      }
      float qv = 0.95f * 63.0f;
      float hw = qv - 59.0f;
      float lw = 1.0f - hw;
      float tq0 = s0_59 * lw + s0_60 * hw;
      float tq1 = s1_59 * lw + s1_60 * hw;
      sTilt[wv * 65 + lane] = fminf(vo0, tq0);
      sTilt[(wv + 16) * 65 + lane] = fminf(vo1, tq1);
    }
    __syncthreads();

    // ---- P3: 8 rejection attempts (4 cand/thread) + Poisson on tid<32
    {
      float plk[17];
      if (tid < 32) {
#pragma unroll
        for (int k = 0; k < 17; ++k) plk[k] = ws[F_LK + ((ti * 32 + b) * 17 + k) * 32 + tid];
      }
#pragma unroll
      for (int q = 0; q < 4; ++q) {
        int tau = tid + q * 1024;
        int d = (tau >> 3) & 31;
        float A = sA[d], K1 = sK1[d];
        float K1sq = K1 * K1;
        float rp2 = cRp2[q];
        float den = fmaxf(1.0f - ((2.0f * A) * rp2) * SIG2F, 1e-6f);
        float Cv = xla_exp(((K1sq * rp2) * SIG2F) / (2.0f * den)) / cSq[q];
        float p = fminf(Cv / sMb[d], 1.0f);
        sSel[tau] = (cU2[q] < p) ? rp2 : -rp2;
      }
      if (tid < 32) {
        float sum = 0.0f;
        for (int s = 0; s < 64; ++s) sum = sum + sTilt[tid * 65 + s];
        float tilt = sum / 64.0f;
        float lam = (tilt * RATE1F) * dt;
        float negl = -lam;
        int n = 0;
#pragma unroll
        for (int k = 0; k < 17; ++k) n += (plk[k] > negl) ? 1 : 0;
        sNj[tid] = n;
      }
    }
    __syncthreads();

    // ---- P4: select first accept + conditional gaussian; tid512 spins next slab
    if (tid < 512) {
      int jd = tid, d = jd & 31;
      float rp2sel = 0.1f * 0.1f;
      bool found = false;
#pragma unroll
      for (int a = 0; a < 8; ++a) {
        float v = sSel[jd * 8 + a];
        if (!found && v > 0.0f) { rp2sel = v; found = true; }
      }
      float A = sA[d], K1 = sK1[d];
      float t2 = (2.0f * rp2sel) * SIG2F;
      float K2 = A - 1.0f / t2;
      float K2s = (K2 < -1e-6f) ? K2 : -1e-6f;
      float mean = (-K1) / (2.0f * K2s);
      float var = (-1.0f) / (2.0f * K2s);
      float cond = mean + sqrt_cr(var) * cZ;
      bool mk = (jd >> 5) < sNj[d];
      sCond[jd] = cond * (mk ? 1.0f : 0.0f);
    } else if (tid == 512 && ti < 63) {
      spin_ge(&cnt[ti + 1], NPROD);
    }
    __syncthreads();

    // ---- prefetch next slab + P5 (state update)
    int tn = (ti < 63) ? ti + 1 : 63;
    float nSc0, nSc1, nSc2, nQd0, nQd1, nQd2, nRp2[4], nSq[4], nU2[4], nZ;
    float nA = 0.0f, nB = 0.0f;
    {
      int tb = tn * 32 + b;
      nSc0 = ws[F_SCALED + tb * 2048 + tid];
      nQd0 = ws[F_QUAD + tb * 2048 + tid];
      nSc1 = (tid < 960) ? ws[F_SCALED + tb * 2048 + 960 + tid] : 0.0f;
      nQd1 = (tid < 960) ? ws[F_QUAD + tb * 2048 + 960 + tid] : 0.0f;
      nSc2 = (tid < 128) ? ws[F_SCALED + tb * 2048 + 1920 + tid] : 0.0f;
      nQd2 = (tid < 128) ? ws[F_QUAD + tb * 2048 + 1920 + tid] : 0.0f;
#pragma unroll
      for (int q = 0; q < 4; ++q) {
        nRp2[q] = ws[F_RP2 + tb * 4096 + tid + q * 1024];
        nSq[q]  = ws[F_SQ + tb * 4096 + tid + q * 1024];
        nU2[q]  = ws[F_U2 + tb * 4096 + tid + q * 1024];
      }
      nZ = ws[F_Z + tb * 512 + zi];
      if (tid < 32) { nA = ws[F_A + tn * 32 + tid]; nB = ws[F_B + tn * 32 + tid]; }
    }
    if (tid < 32) {
      int d = tid;
      float soj = 0.0f;
      for (int j = 0; j < 16; ++j) soj = soj + sCond[j * 32 + d];
      soj = 2.5f * xla_tanh(soj / 2.5f);
      float Xn = (sX[d] + sDrift[d] * dt) + sDs[d] * soj;
      sX[d] = Xn;
      out[ti * 1024 + b * 32 + d] = Xn;
      sA[d] = nA;
      float K1n = (2.0f * nA) * Xn + nB;
      sK1[d] = K1n;
      sMb[d] = xla_exp((-(K1n * K1n)) / (4.0f * nA));
    }
    __syncthreads();

    cSc0 = nSc0; cSc1 = nSc1; cSc2 = nSc2;
    cQd0 = nQd0; cQd1 = nQd1; cQd2 = nQd2;
#pragma unroll
    for (int q = 0; q < 4; ++q) { cRp2[q] = nRp2[q]; cSq[q] = nSq[q]; cU2[q] = nU2[q]; }
    cZ = nZ;
    past_t = t;
  }
}

// ================================================================ M2 fallback (R3, proven)
#define OFF_A    0
#define OFF_B    2048
#define OFF_DS   4096
#define OFF_KEYS 4128
#define OFF_KA   4640
#define OFF_KP   5664
#define OFF_SUB  6688
#define OFF_RAW  16384
#define OFF_RP   4210688
#define OFF_LK   12599296
#define OFF_U2   13713408
#define OFF_Z    22102016
#define WS_FLOATS_M2 23150592
#define NRAW 4194304
#define NRP  8388608
#define NU2  8388608
#define NZ   1048576
#define NLK  65536

__global__ void __launch_bounds__(64) key_kernel(unsigned* __restrict__ wsu) {
  __shared__ unsigned lk[64][2];
  int t = threadIdx.x;
  if (t == 0) {
    unsigned k0 = 0u, k1 = 42u;
    for (int i = 0; i < 64; ++i) {
      lk[i][0] = k0; lk[i][1] = k1;
      U2 c0 = tf2(k0, k1, 0u, 0u);
      k0 = c0.a; k1 = c0.b;
    }
  }
  __syncthreads();
  unsigned k0 = lk[t][0], k1 = lk[t][1];
  U2 c1 = tf2(k0, k1, 0u, 1u);
  U2 c2 = tf2(k0, k1, 0u, 2u);
  U2 c3 = tf2(k0, k1, 0u, 3u);
  U2 c4 = tf2(k0, k1, 0u, 4u);
  wsu[OFF_KEYS + t * 8 + 0] = c1.a; wsu[OFF_KEYS + t * 8 + 1] = c1.b;
  wsu[OFF_KEYS + t * 8 + 2] = c2.a; wsu[OFF_KEYS + t * 8 + 3] = c2.b;
  wsu[OFF_KEYS + t * 8 + 4] = c3.a; wsu[OFF_KEYS + t * 8 + 5] = c3.b;
  wsu[OFF_KEYS + t * 8 + 6] = c4.a; wsu[OFF_KEYS + t * 8 + 7] = c4.b;
  unsigned a0 = c3.a, a1 = c3.b;
  for (int a = 0; a < 8; ++a) {
    U2 kp = tf2(a0, a1, 0u, 1u);
    U2 ka = tf2(a0, a1, 0u, 2u);
    U2 nx = tf2(a0, a1, 0u, 0u);
    wsu[OFF_KP + (t * 8 + a) * 2 + 0] = kp.a; wsu[OFF_KP + (t * 8 + a) * 2 + 1] = kp.b;
    wsu[OFF_KA + (t * 8 + a) * 2 + 0] = ka.a; wsu[OFF_KA + (t * 8 + a) * 2 + 1] = ka.b;
    a0 = nx.a; a1 = nx.b;
  }
  unsigned r0 = c2.a, r1 = c2.b;
  for (int k = 0; k < 17; ++k) {
    U2 sub = tf2(r0, r1, 0u, 1u);
    U2 nx  = tf2(r0, r1, 0u, 0u);
    wsu[OFF_SUB + (t * 17 + k) * 2 + 0] = sub.a; wsu[OFF_SUB + (t * 17 + k) * 2 + 1] = sub.b;
    r0 = nx.a; r1 = nx.b;
  }
}

__global__ void __launch_bounds__(256) stable_kernel(const unsigned* __restrict__ wsu,
                                                     float* __restrict__ ws) {
  const int NTOT = NRAW + NRP + NU2 + NZ + NLK;
  int stride = gridDim.x * blockDim.x;
  for (int idx = blockIdx.x * blockDim.x + threadIdx.x; idx < NTOT; idx += stride) {
    if (idx < NRAW) {
      int t = idx >> 16;
      int b = (idx >> 11) & 31;
      int e = idx & 2047;
      unsigned k0 = wsu[OFF_KEYS + t * 8 + 0], k1 = wsu[OFF_KEYS + t * 8 + 1];
      float u = u01(rbits(k0, k1, (unsigned)(b * 2048 + e)));
      ws[OFF_RAW + idx] = 0.1f * powm(1.0f - u);
    } else if (idx < NRAW + NRP) {
      int i2 = idx - NRAW;
      int t = i2 >> 17;
      int b = (i2 >> 12) & 31;
      int jd = (i2 >> 3) & 511;
      int a = i2 & 7;
      unsigned k0 = wsu[OFF_KP + (t * 8 + a) * 2], k1 = wsu[OFF_KP + (t * 8 + a) * 2 + 1];
      float u1 = u01(rbits(k0, k1, (unsigned)(b * 512 + jd)));
      ws[OFF_RP + i2] = 0.1f * powm(1.0f - u1);
    } else if (idx < NRAW + NRP + NU2) {
      int i3 = idx - (NRAW + NRP);
      int t = i3 >> 17;
      int b = (i3 >> 12) & 31;
      int jd = (i3 >> 3) & 511;
      int a = i3 & 7;
      unsigned k0 = wsu[OFF_KA + (t * 8 + a) * 2], k1 = wsu[OFF_KA + (t * 8 + a) * 2 + 1];
      ws[OFF_U2 + i3] = u01(rbits(k0, k1, (unsigned)(b * 512 + jd)));
    } else if (idx < NRAW + NRP + NU2 + NZ) {
      int i4 = idx - (NRAW + NRP + NU2);
      int t = i4 >> 14;
      int b = (i4 >> 9) & 31;
      int jd = i4 & 511;
      unsigned k0 = wsu[OFF_KEYS + t * 8 + 6], k1 = wsu[OFF_KEYS + t * 8 + 7];
      float fz = u01(rbits(k0, k1, (unsigned)(b * 512 + jd)));
      float un = fmaxf(LO_N, fz * 2.0f + LO_N);
      ws[OFF_Z + i4] = SQRT2F * xla_erfinv(un);
    } else {
      int i5 = idx - (NRAW + NRP + NU2 + NZ);
      int t = i5 >> 10;
      int b = (i5 >> 5) & 31;
      int d = i5 & 31;
      float L = 0.0f;
      for (int k = 0; k < 17; ++k) {
        unsigned s0 = wsu[OFF_SUB + (t * 17 + k) * 2], s1 = wsu[OFF_SUB + (t * 17 + k) * 2 + 1];
        float u = u01(rbits(s0, s1, (unsigned)(b * 32 + d)));
        L = L + xla_log(u);
        ws[OFF_LK + ((t * 32 + b) * 17 + k) * 32 + d] = L;
      }
    }
  }
}

__global__ void __launch_bounds__(64) phi_kernel(
    const float* __restrict__ tseq,
    const float* __restrict__ pW1, const float* __restrict__ pb1,
    const float* __restrict__ pW2, const float* __restrict__ pb2,
    const float* __restrict__ pW3, const float* __restrict__ pb3,
    const float* __restrict__ diff_log, float* __restrict__ ws) {
  __shared__ float h1[64], h2[64];
  int t = blockIdx.x, w = threadIdx.x;
  float tv = tseq[t];
  h1[w] = xla_tanh(tv * pW1[w] + pb1[w]);
  __syncthreads();
  float acc = 0.0f;
  for (int k = 0; k < 64; ++k) acc = fmaf(h1[k], pW2[k * 64 + w], acc);
  acc = acc + pb2[w];
  h2[w] = xla_tanh(acc);
  __syncthreads();
  acc = 0.0f;
  for (int k = 0; k < 64; ++k) acc = fmaf(h2[k], pW3[k * 64 + w], acc);
  acc = acc + pb3[w];
  if (w < 32) ws[OFF_A + t * 32 + w] = -softplus_ref(acc);
  else        ws[OFF_B + t * 32 + (w - 32)] = acc;
  if (t == 0 && w < 32) ws[OFF_DS + w] = softplus_ref(diff_log[w]);
}

__global__ void __launch_bounds__(1024) sim2_kernel(
    const float* __restrict__ state_init, const float* __restrict__ tseq,
    const float* __restrict__ gW1, const float* __restrict__ gb1,
    const float* __restrict__ gW2, const float* __restrict__ gb2,
    const float* __restrict__ gW3, const float* __restrict__ gb3,
    const float* __restrict__ ws, float* __restrict__ out) {
  const int b = blockIdx.x;
  const int tid = threadIdx.x;

  __shared__ float sW1[33 * 64], sB1[64], sW2[64 * 64], sB2[64], sW3[64 * 32], sB3[32];
  __shared__ float sTseq[64];
  __shared__ float sX[32], sK1[32], sA[32], sMb[32], sDrift[32], sDs[32];
  __shared__ int   sNj[32];
  __shared__ float sH1[64], sH2[64];
  __shared__ float sTilt[32 * 65];
  __shared__ float sRp[4096];
  __shared__ float sCond[512];

  for (int i = tid; i < 33 * 64; i += 1024) sW1[i] = gW1[i];
  for (int i = tid; i < 64 * 64; i += 1024) sW2[i] = gW2[i];
  for (int i = tid; i < 64 * 32; i += 1024) sW3[i] = gW3[i];
  if (tid < 64) { sB1[tid] = gb1[tid]; sB2[tid] = gb2[tid]; sTseq[tid] = tseq[tid]; }
  if (tid < 32) { sB3[tid] = gb3[tid]; sX[tid] = state_init[b * 32 + tid]; sDs[tid] = ws[OFF_DS + tid]; }
  __syncthreads();

  if (tid < 32) {
    float A = ws[OFF_A + tid], Bv = ws[OFF_B + tid];
    sA[tid] = A;
    float K1 = (2.0f * A) * sX[tid] + Bv;
    sK1[tid] = K1;
    sMb[tid] = xla_exp((-(K1 * K1)) / (4.0f * A));
  }

  int zi = tid & 511;
  float cRaw0, cRaw1, cRaw2, cRp[4], cU2[4], cZ;
  {
    int rawb = OFF_RAW + b * 2048;
    cRaw0 = ws[rawb + tid];
    cRaw1 = (tid < 960) ? ws[rawb + 960 + tid] : 0.0f;
    cRaw2 = (tid < 128) ? ws[rawb + 1920 + tid] : 0.0f;
    int cb = b * 4096;
#pragma unroll
    for (int q = 0; q < 4; ++q) {
      cRp[q] = ws[OFF_RP + cb + tid + q * 1024];
      cU2[q] = ws[OFF_U2 + cb + tid + q * 1024];
    }
    cZ = ws[OFF_Z + b * 512 + zi];
  }
  __syncthreads();

  float past_t = sTseq[0];

  for (int ti = 0; ti < Tn; ++ti) {
    float t = sTseq[ti];
    float dt = t - past_t;

    int tn = (ti < 63) ? ti + 1 : 63;
    float nRaw0, nRaw1, nRaw2, nRp[4], nU2[4], nZ, nA = 0.0f, nB = 0.0f;
    {
      int rawb = OFF_RAW + (tn * 32 + b) * 2048;
      nRaw0 = ws[rawb + tid];
      nRaw1 = (tid < 960) ? ws[rawb + 960 + tid] : 0.0f;
      nRaw2 = (tid < 128) ? ws[rawb + 1920 + tid] : 0.0f;
      int cb = (tn * 32 + b) * 4096;
#pragma unroll
      for (int q = 0; q < 4; ++q) {
        nRp[q] = ws[OFF_RP + cb + tid + q * 1024];
        nU2[q] = ws[OFF_U2 + cb + tid + q * 1024];
      }
      nZ = ws[OFF_Z + (tn * 32 + b) * 512 + zi];
      if (tid < 32) { nA = ws[OFF_A + tn * 32 + tid]; nB = ws[OFF_B + tn * 32 + tid]; }
    }

    if (tid >= 960) {
      int l = tid - 960;
      float acc = 0.0f;
      acc = fmaf(t, sW1[l], acc);
      for (int k = 1; k < 33; ++k) acc = fmaf(sX[k - 1], sW1[k * 64 + l], acc);
      acc = acc + sB1[l];
      sH1[l] = xla_tanh(acc);
      float acc2 = 0.0f;
      for (int k = 0; k < 64; ++k) acc2 = fmaf(sH1[k], sW2[k * 64 + l], acc2);
      acc2 = acc2 + sB2[l];
      sH2[l] = xla_tanh(acc2);
      if (l < 32) {
        float a3 = 0.0f;
        for (int k = 0; k < 64; ++k) a3 = fmaf(sH2[k], sW3[k * 32 + l], a3);
        a3 = a3 + sB3[l];
        sDrift[l] = a3;
      }
    } else {
      int d0 = tid & 31;
      float K1 = sK1[d0], A = sA[d0], dsv = sDs[d0];
      {
        float scaled = dsv * cRaw0;
        float quad = A * (scaled * scaled);
        float lin = K1 * scaled;
        float lh = 80.0f * xla_tanh((quad + lin) / 80.0f);
        float nh = 80.0f * xla_tanh((quad - lin) / 80.0f);
        sTilt[d0 * 65 + (tid >> 5)] = xla_exp(lh) + xla_exp(nh);
      }
      {
        int e = tid + 960, d = e & 31;
        float K1b = sK1[d], Ab = sA[d], dsb = sDs[d];
        float scaled = dsb * cRaw1;
        float quad = Ab * (scaled * scaled);
        float lin = K1b * scaled;
        float lh = 80.0f * xla_tanh((quad + lin) / 80.0f);
        float nh = 80.0f * xla_tanh((quad - lin) / 80.0f);
        sTilt[d * 65 + (e >> 5)] = xla_exp(lh) + xla_exp(nh);
      }
      if (tid < 128) {
        int e = 1920 + tid, d = e & 31;
        float K1b = sK1[d], Ab = sA[d], dsb = sDs[d];
        float scaled = dsb * cRaw2;
        float quad = Ab * (scaled * scaled);
        float lin = K1b * scaled;
        float lh = 80.0f * xla_tanh((quad + lin) / 80.0f);
        float nh = 80.0f * xla_tanh((quad - lin) / 80.0f);
        sTilt[d * 65 + (e >> 5)] = xla_exp(lh) + xla_exp(nh);
      }
    }
    __syncthreads();

    {
      int wv = tid >> 6, lane = tid & 63;
      float vo0 = sTilt[wv * 65 + lane];
      float vo1 = sTilt[(wv + 16) * 65 + lane];
      float v0 = vo0, v1 = vo1;
      for (int k = 2; k <= 64; k <<= 1)
        for (int j = k >> 1; j > 0; j >>= 1) {
          float o0 = __shfl_xor(v0, j, 64);
          float o1 = __shfl_xor(v1, j, 64);
          bool keepmin = (((lane & j) == 0) == ((lane & k) == 0));
          v0 = keepmin ? fminf(v0, o0) : fmaxf(v0, o0);
          v1 = keepmin ? fminf(v1, o1) : fmaxf(v1, o1);
        }
      float qv = 0.95f * 63.0f;
      float hw = qv - 59.0f;
      float lw = 1.0f - hw;
      float s59 = __shfl(v0, 59, 64), s60 = __shfl(v0, 60, 64);
      float tq0 = s59 * lw + s60 * hw;
      s59 = __shfl(v1, 59, 64); s60 = __shfl(v1, 60, 64);
      float tq1 = s59 * lw + s60 * hw;
      sTilt[wv * 65 + lane] = fminf(vo0, tq0);
      sTilt[(wv + 16) * 65 + lane] = fminf(vo1, tq1);
    }
    __syncthreads();

    {
#pragma unroll
      for (int q = 0; q < 4; ++q) {
        int tau = tid + q * 1024;
        int d = (tau >> 3) & 31;
        float A = sA[d], K1 = sK1[d];
        float K1sq = K1 * K1;
        float rp = cRp[q];
        float rp2 = rp * rp;
        float den = fmaxf(1.0f - ((2.0f * A) * rp2) * SIG2F, 1e-6f);
        float Cv = xla_exp(((K1sq * rp2) * SIG2F) / (2.0f * den)) / sqrt_cr(den);
        float p = fminf(Cv / sMb[d], 1.0f);
        sRp[tau] = (cU2[q] < p) ? rp : -rp;
      }
      if (tid < 32) {
        float lk[17];
#pragma unroll
        for (int k = 0; k < 17; ++k) lk[k] = ws[OFF_LK + ((ti * 32 + b) * 17 + k) * 32 + tid];
        float sum = 0.0f;
        for (int s = 0; s < 64; ++s) sum = sum + sTilt[tid * 65 + s];
        float tilt = sum / 64.0f;
        float lam = (tilt * RATE1F) * dt;
        float negl = -lam;
        int n = 0;
#pragma unroll
        for (int k = 0; k < 17; ++k) n += (lk[k] > negl) ? 1 : 0;
        sNj[tid] = n;
      }
    }
    __syncthreads();

    if (tid < 512) {
      int jd = tid, d = jd & 31;
      float r = 0.1f;
      bool found = false;
#pragma unroll
      for (int a = 0; a < 8; ++a) {
        float v = sRp[jd * 8 + a];
        if (!found && v > 0.0f) { r = v; found = true; }
      }
      float z = cZ;
      float A = sA[d], K1 = sK1[d];
      float t2 = (2.0f * (r * r)) * SIG2F;
      float K2 = A - 1.0f / t2;
      float K2s = (K2 < -1e-6f) ? K2 : -1e-6f;
      float mean = (-K1) / (2.0f * K2s);
      float var = (-1.0f) / (2.0f * K2s);
      float cond = mean + sqrt_cr(var) * z;
      bool mk = (jd >> 5) < sNj[d];
      sCond[jd] = cond * (mk ? 1.0f : 0.0f);
    }
    __syncthreads();

    if (tid < 32) {
      int d = tid;
      float soj = 0.0f;
      for (int j = 0; j < 16; ++j) soj = soj + sCond[j * 32 + d];
      soj = 2.5f * xla_tanh(soj / 2.5f);
      float Xn = (sX[d] + sDrift[d] * dt) + sDs[d] * soj;
      sX[d] = Xn;
      out[ti * 1024 + b * 32 + d] = Xn;
      sA[d] = nA;
      float K1n = (2.0f * nA) * Xn + nB;
      sK1[d] = K1n;
      sMb[d] = xla_exp((-(K1n * K1n)) / (4.0f * nA));
    }
    __syncthreads();

    cRaw0 = nRaw0; cRaw1 = nRaw1; cRaw2 = nRaw2;
#pragma unroll
    for (int q = 0; q < 4; ++q) { cRp[q] = nRp[q]; cU2[q] = nU2[q]; }
    cZ = nZ;
    past_t = t;
  }
}

// ---------------------------------------------------------------- launch
extern "C" void kernel_launch(void* const* d_in, const int* in_sizes, int n_in,
                              void* d_out, int out_size, void* d_ws, size_t ws_size,
                              hipStream_t stream) {
  const float* state_init = (const float*)d_in[0];
  const float* tseq       = (const float*)d_in[1];
  const float* dW1        = (const float*)d_in[2];
  const float* db1        = (const float*)d_in[3];
  const float* dW2        = (const float*)d_in[4];
  const float* db2        = (const float*)d_in[5];
  const float* dW3        = (const float*)d_in[6];
  const float* db3        = (const float*)d_in[7];
  const float* diff_log   = (const float*)d_in[8];
  const float* pW1        = (const float*)d_in[9];
  const float* pb1        = (const float*)d_in[10];
  const float* pW2        = (const float*)d_in[11];
  const float* pb2        = (const float*)d_in[12];
  const float* pW3        = (const float*)d_in[13];
  const float* pb3        = (const float*)d_in[14];
  float* ws = (float*)d_ws;
  unsigned* wsu = (unsigned*)d_ws;
  float* outp = (float*)d_out;

  bool fat = ws_size >= (size_t)F_END * 4;
  if (fat) {
    (void)hipMemsetAsync((char*)d_ws + (size_t)F_CNT * 4, 0, 65 * 4, stream);
    void* args[] = {
      (void*)&state_init, (void*)&tseq,
      (void*)&dW1, (void*)&db1, (void*)&dW2, (void*)&db2,
      (void*)&dW3, (void*)&db3, (void*)&diff_log,
      (void*)&pW1, (void*)&pb1, (void*)&pW2, (void*)&pb2,
      (void*)&pW3, (void*)&pb3, (void*)&ws, (void*)&outp
    };
    hipError_t e = hipLaunchCooperativeKernel((const void*)fat_kernel,
                                              dim3(256), dim3(1024), args, 0, stream);
    if (e == hipSuccess) return;
    (void)hipGetLastError();
  }
  // fallback: R3 proven path
  key_kernel<<<1, 64, 0, stream>>>(wsu);
  phi_kernel<<<64, 64, 0, stream>>>(tseq, pW1, pb1, pW2, pb2, pW3, pb3, diff_log, ws);
  stable_kernel<<<4096, 256, 0, stream>>>(wsu, ws);
  sim2_kernel<<<32, 1024, 0, stream>>>(state_init, tseq, dW1, db1, dW2, db2,
                                       dW3, db3, ws, outp);
}

// Round 6
// 737.447 us; speedup vs baseline: 1.7910x; 1.7910x over previous
//
#include <hip/hip_runtime.h>
#include <cstdint>
#include <math.h>

// XLA CPU (no fast-math) emits unfused mul/add for all HLO-level elementwise ops.
#pragma clang fp contract(off)

#define DEV __device__ __forceinline__

// ---------------------------------------------------------------- threefry2x32
struct U2 { unsigned a, b; };

DEV unsigned rotl32(unsigned v, int d) { return (v << d) | (v >> (32 - d)); }

DEV U2 tf2(unsigned k0, unsigned k1, unsigned x0, unsigned x1) {
  unsigned ks2 = k0 ^ k1 ^ 0x1BD11BDAu;
  x0 += k0; x1 += k1;
#define TFR(r) { x0 += x1; x1 = rotl32(x1, r); x1 ^= x0; }
  TFR(13) TFR(15) TFR(26) TFR(6)
  x0 += k1; x1 += ks2 + 1u;
  TFR(17) TFR(29) TFR(16) TFR(24)
  x0 += ks2; x1 += k0 + 2u;
  TFR(13) TFR(15) TFR(26) TFR(6)
  x0 += k0; x1 += k1 + 3u;
  TFR(17) TFR(29) TFR(16) TFR(24)
  x0 += k1; x1 += ks2 + 4u;
  TFR(13) TFR(15) TFR(26) TFR(6)
  x0 += ks2; x1 += k0 + 5u;
#undef TFR
  U2 r; r.a = x0; r.b = x1; return r;
}

DEV unsigned rbits(unsigned k0, unsigned k1, unsigned idx) {
  U2 o = tf2(k0, k1, 0u, idx);
  return o.a ^ o.b;
}

DEV float u01(unsigned bits) {
  return __uint_as_float((bits >> 9) | 0x3F800000u) - 1.0f;
}

// ---------------------------------------------------------------- XLA CPU math
DEV float xla_exp(float xi) {
  float x = fminf(fmaxf(xi, -88.3762626647949f), 88.3762626647950f);
  float fx = floorf(x * 1.44269504088896341f + 0.5f);
  float tmp = 0.693359375f * fx;
  float z = -2.12194440e-4f * fx;
  x = x - tmp;
  x = x - z;
  z = x * x;
  float y = 1.9875691500e-4f * x + 1.3981999507e-3f;
  y = y * x + 8.3334519073e-3f;
  y = y * x + 4.1665795894e-2f;
  y = y * x + 1.6666665459e-1f;
  y = y * x + 5.0000001201e-1f;
  y = y * z + x;
  y = y + 1.0f;
  int n = (int)fx;
  float two_n = __uint_as_float((unsigned)(n + 127) << 23);
  return fmaxf(y * two_n, xi);
}

DEV float xla_log(float xi) {
  float xc = fmaxf(xi, 1.17549435082228751e-38f);
  unsigned bits = __float_as_uint(xc);
  float e = (float)((int)(bits >> 23) - 126);
  float m = __uint_as_float((bits & 0x007FFFFFu) | 0x3F000000u);
  bool msk = m < 0.707106781186547524f;
  float tmp = msk ? m : 0.0f;
  float em  = msk ? 1.0f : 0.0f;
  m = m - 1.0f;
  e = e - em;
  m = m + tmp;
  float z  = m * m;
  float x3 = z * m;
  float y0 = 7.0376836292e-2f  * m + -1.1514610310e-1f;
  float y1 = -1.2420140846e-1f * m + 1.4249322787e-1f;
  float y2 = 2.0000714765e-1f  * m + -2.4999993993e-1f;
  y0 = y0 * m + 1.1676998740e-1f;
  y1 = y1 * m + -1.6668057665e-1f;
  y2 = y2 * m + 3.3333331174e-1f;
  y0 = y0 * x3 + y1;
  y0 = y0 * x3 + y2;
  y0 = y0 * x3;
  y0 = -2.12194440e-4f * e + y0;
  y0 = y0 - 0.5f * z;
  float r = m + y0;
  r = 0.693359375f * e + r;
  if (!(xi > 0.0f)) r = (xi == 0.0f) ? -__builtin_inff() : __builtin_nanf("");
  if (xi == __builtin_inff()) r = __builtin_inff();
  return r;
}

DEV float xla_tanh(float x) {
  float xc = fminf(fmaxf(x, -9.0f), 9.0f);
  float x2 = xc * xc;
  float p = x2 * -2.76076847742355e-16f + 2.00018790482477e-13f;
  p = p * x2 + -8.60467152213735e-11f;
  p = p * x2 + 5.12229709037114e-08f;
  p = p * x2 + 1.48572235717979e-05f;
  p = p * x2 + 6.37261928875436e-04f;
  p = p * x2 + 4.89352455891786e-03f;
  p = xc * p;
  float q = x2 * 1.19825839466702e-06f + 1.18534705686654e-04f;
  q = q * x2 + 2.26843463243900e-03f;
  q = q * x2 + 4.89352518554385e-03f;
  float r = p / q;
  return (fabsf(x) < 0.0004f) ? x : r;
}

DEV float sqrt_cr(float x) { return (float)sqrt((double)x); }

DEV float xla_log1p(float x) {
  float fl = xla_log(x + 1.0f);
  float fs = ((-0.5f) * x + 1.0f) * x;
  return (fabsf(x) < 1e-4f) ? fs : fl;
}

DEV float softplus_ref(float x) {
  float amax = fmaxf(x, 0.0f);
  return amax + xla_log1p(xla_exp(-fabsf(x)));
}

DEV float xla_erfinv(float x) {
  float w = -xla_log1p(-(x * x));
  bool lt = w < 5.0f;
  float wa = lt ? (w - 2.5f) : (sqrt_cr(w) - 3.0f);
  float p;
  if (lt) {
    p = 2.81022636e-08f;
    p = p * wa + 3.43273939e-07f;
    p = p * wa + -3.5233877e-06f;
    p = p * wa + -4.39150654e-06f;
    p = p * wa + 0.00021858087f;
    p = p * wa + -0.00125372503f;
    p = p * wa + -0.00417768164f;
    p = p * wa + 0.246640727f;
    p = p * wa + 1.50140941f;
  } else {
    p = -0.000200214257f;
    p = p * wa + 0.000100950558f;
    p = p * wa + 0.00134934322f;
    p = p * wa + -0.00367342844f;
    p = p * wa + 0.00573950773f;
    p = p * wa + -0.0076224613f;
    p = p * wa + 0.00943887047f;
    p = p * wa + 1.00167406f;
    p = p * wa + 2.83297682f;
  }
  return p * x;
}

// ---------------------------------------------------------------- custom f64 pow
// x^E for x in (2^-24, 1], E = -(float)(1/1.2). Accuracy ~2-3 f64 ulp — float
// result after (float)-cast matches OCML/libm pow except w/ prob ~2e-8/draw of
// a 1-float-ulp diff (continuous downstream effect only; threshold margin 1e5).
DEV float powm_fast(float xf) {
  const double E = (double)((float)(-1.0 / 1.2));
  double x = (double)xf;
  long long bits = __double_as_longlong(x);
  int k = (int)((bits >> 52) & 0x7FFLL) - 1023;
  double m = __longlong_as_double((bits & 0x000FFFFFFFFFFFFFLL) | 0x3FF0000000000000LL);
  if (m > 1.4142135623730951) { m = m * 0.5; k = k + 1; }
  double z = (m - 1.0) / (m + 1.0);
  double z2 = z * z;
  // log2(m) = z * P(z2), P Taylor of 2*atanh scaled by 1/ln2
  double pl = 0.11541560327111707;
  pl = fma(pl, z2, 0.12545174268599682);
  pl = fma(pl, z2, 0.13739952770371080);
  pl = fma(pl, z2, 0.15186263588304878);
  pl = fma(pl, z2, 0.16972882833987805);
  pl = fma(pl, z2, 0.19235933878519512);
  pl = fma(pl, z2, 0.22195308321368668);
  pl = fma(pl, z2, 0.26230818925253880);
  pl = fma(pl, z2, 0.32059889797532520);
  pl = fma(pl, z2, 0.41219858311113240);
  pl = fma(pl, z2, 0.57707801635558537);
  pl = fma(pl, z2, 0.96179669392597556);
  pl = fma(pl, z2, 2.88539008177792681);
  double t = (double)k + z * pl;
  double yh = E * t;                    // y in [0, ~20.3]
  double yl = fma(E, t, -yh);
  double fn = floor(yh + 0.5);
  double f = yh - fn;
  double w = f * 0.69314718055994531;
  double ew = 1.6059043836821613e-10;   // 1/13!
  ew = fma(ew, w, 2.0876756987868099e-9);
  ew = fma(ew, w, 2.5052108385441719e-8);
  ew = fma(ew, w, 2.7557319223985893e-7);
  ew = fma(ew, w, 2.7557319223985888e-6);
  ew = fma(ew, w, 2.4801587301587302e-5);
  ew = fma(ew, w, 1.9841269841269841e-4);
  ew = fma(ew, w, 1.3888888888888889e-3);
  ew = fma(ew, w, 8.3333333333333332e-3);
  ew = fma(ew, w, 4.1666666666666664e-2);
  ew = fma(ew, w, 0.16666666666666666);
  ew = fma(ew, w, 0.5);
  ew = fma(ew, w, 1.0);
  ew = fma(ew, w, 1.0);
  int n = (int)fn;
  double r = ew * __longlong_as_double((long long)(n + 1023) << 52);
  r = fma(r, yl * 0.69314718055994531, r);
  return (float)r;
}

// ---------------------------------------------------------------- constants
#define SIG2F  0.0025000000000000005f
#define RATE1F 13.207443270509278f
#define LO_N  -0.99999994039535522f
#define SQRT2F 1.4142135623730951f
#define Tn 64

// ---------------------------------------------------------------- ws layout (floats)
#define F_A      0          // 2048
#define F_B      2048       // 2048
#define F_DS     4096       // 32
#define F_KEYS   4128       // 512 u
#define F_KA     4640       // 1024 u
#define F_KP     5664       // 1024 u
#define F_SUB    6688       // 2176 u
#define F_SCALED 16384      // 4194304
#define F_QUAD   4210688    // 4194304
#define F_RP2    8404992    // 8388608
#define F_SQ     16793600   // 8388608
#define F_U2     25182208   // 8388608
#define F_Z      33570816   // 1048576
#define F_LK     34619392   // 1114112
#define F_END    35733504   // 143 MB — proven available (R5 fat path ran)

// ---------------------------------------------------------------- key tables
__global__ void __launch_bounds__(64) key_kernel(unsigned* __restrict__ wsu) {
  __shared__ unsigned lk[64][2];
  int t = threadIdx.x;
  if (t == 0) {
    unsigned k0 = 0u, k1 = 42u;   // jax.random.key(42)
    for (int i = 0; i < 64; ++i) {
      lk[i][0] = k0; lk[i][1] = k1;
      U2 c0 = tf2(k0, k1, 0u, 0u);
      k0 = c0.a; k1 = c0.b;
    }
  }
  __syncthreads();
  unsigned k0 = lk[t][0], k1 = lk[t][1];
  U2 c1 = tf2(k0, k1, 0u, 1u);  // k_stab
  U2 c2 = tf2(k0, k1, 0u, 2u);  // k_pois
  U2 c3 = tf2(k0, k1, 0u, 3u);  // k_rej
  U2 c4 = tf2(k0, k1, 0u, 4u);  // k_gauss
  wsu[F_KEYS + t * 8 + 0] = c1.a; wsu[F_KEYS + t * 8 + 1] = c1.b;
  wsu[F_KEYS + t * 8 + 2] = c2.a; wsu[F_KEYS + t * 8 + 3] = c2.b;
  wsu[F_KEYS + t * 8 + 4] = c3.a; wsu[F_KEYS + t * 8 + 5] = c3.b;
  wsu[F_KEYS + t * 8 + 6] = c4.a; wsu[F_KEYS + t * 8 + 7] = c4.b;
  unsigned a0 = c3.a, a1 = c3.b;
  for (int a = 0; a < 8; ++a) {
    U2 kp = tf2(a0, a1, 0u, 1u);
    U2 ka = tf2(a0, a1, 0u, 2u);
    U2 nx = tf2(a0, a1, 0u, 0u);
    wsu[F_KP + (t * 8 + a) * 2 + 0] = kp.a; wsu[F_KP + (t * 8 + a) * 2 + 1] = kp.b;
    wsu[F_KA + (t * 8 + a) * 2 + 0] = ka.a; wsu[F_KA + (t * 8 + a) * 2 + 1] = ka.b;
    a0 = nx.a; a1 = nx.b;
  }
  unsigned r0 = c2.a, r1 = c2.b;
  for (int k = 0; k < 17; ++k) {
    U2 sub = tf2(r0, r1, 0u, 1u);
    U2 nx  = tf2(r0, r1, 0u, 0u);
    wsu[F_SUB + (t * 17 + k) * 2 + 0] = sub.a; wsu[F_SUB + (t * 17 + k) * 2 + 1] = sub.b;
    r0 = nx.a; r1 = nx.b;
  }
}

// ---------------------------------------------------------------- phi precompute
__global__ void __launch_bounds__(64) phi_kernel(
    const float* __restrict__ tseq,
    const float* __restrict__ pW1, const float* __restrict__ pb1,
    const float* __restrict__ pW2, const float* __restrict__ pb2,
    const float* __restrict__ pW3, const float* __restrict__ pb3,
    const float* __restrict__ diff_log, float* __restrict__ ws) {
  __shared__ float h1[64], h2[64];
  int t = blockIdx.x, w = threadIdx.x;
  float tv = tseq[t];
  h1[w] = xla_tanh(tv * pW1[w] + pb1[w]);
  __syncthreads();
  float acc = 0.0f;
  for (int k = 0; k < 64; ++k) acc = fmaf(h1[k], pW2[k * 64 + w], acc);
  acc = acc + pb2[w];
  h2[w] = xla_tanh(acc);
  __syncthreads();
  acc = 0.0f;
  for (int k = 0; k < 64; ++k) acc = fmaf(h2[k], pW3[k * 64 + w], acc);
  acc = acc + pb3[w];
  if (w < 32) ws[F_A + t * 32 + w] = -softplus_ref(acc);
  else        ws[F_B + t * 32 + (w - 32)] = acc;
  if (t == 0 && w < 32) ws[F_DS + w] = softplus_ref(diff_log[w]);
}

// ---------------------------------------------------------------- stable precompute
// grid (836, 64): 836*256 = 214016 units per slab t = blockIdx.y
__global__ void __launch_bounds__(256) stable2_kernel(const unsigned* __restrict__ wsu,
                                                      float* __restrict__ ws) {
  int t = blockIdx.y;
  int u = blockIdx.x * 256 + threadIdx.x;
  if (u < 65536) {
    // tilt raw -> scaled, quad
    int b_ = u >> 11, e = u & 2047, d = e & 31;
    unsigned k0 = wsu[F_KEYS + t * 8 + 0], k1 = wsu[F_KEYS + t * 8 + 1];
    float uu = u01(rbits(k0, k1, (unsigned)(b_ * 2048 + e)));
    float raw = 0.1f * powm_fast(1.0f - uu);
    float scaled = ws[F_DS + d] * raw;
    float A = ws[F_A + t * 32 + d];
    ws[F_SCALED + t * 65536 + u] = scaled;
    ws[F_QUAD   + t * 65536 + u] = A * (scaled * scaled);
  } else if (u < 196608) {
    // candidate -> rp2, sq, u2
    int i = u - 65536;
    int b_ = i >> 12, jd = (i >> 3) & 511, a = i & 7, d = jd & 31;
    unsigned p0 = wsu[F_KP + (t * 8 + a) * 2], p1 = wsu[F_KP + (t * 8 + a) * 2 + 1];
    float rp = 0.1f * powm_fast(1.0f - u01(rbits(p0, p1, (unsigned)(b_ * 512 + jd))));
    float rp2 = rp * rp;
    float A = ws[F_A + t * 32 + d];
    float den = fmaxf(1.0f - ((2.0f * A) * rp2) * SIG2F, 1e-6f);
    unsigned a0 = wsu[F_KA + (t * 8 + a) * 2], a1 = wsu[F_KA + (t * 8 + a) * 2 + 1];
    ws[F_RP2 + t * 131072 + i] = rp2;
    ws[F_SQ  + t * 131072 + i] = sqrt_cr(den);   // keep f64 sqrt: feeds accept decision
    ws[F_U2  + t * 131072 + i] = u01(rbits(a0, a1, (unsigned)(b_ * 512 + jd)));
  } else if (u < 212992) {
    // gaussian z
    int i = u - 196608;
    int b_ = i >> 9, jd = i & 511;
    unsigned g0 = wsu[F_KEYS + t * 8 + 6], g1 = wsu[F_KEYS + t * 8 + 7];
    float fz = u01(rbits(g0, g1, (unsigned)(b_ * 512 + jd)));
    float un = fmaxf(LO_N, fz * 2.0f + LO_N);
    ws[F_Z + t * 16384 + i] = SQRT2F * xla_erfinv(un);
  } else {
    // poisson log prefix sums
    int i = u - 212992;
    int b_ = i >> 5, d = i & 31;
    float L = 0.0f;
    for (int k = 0; k < 17; ++k) {
      unsigned s0 = wsu[F_SUB + (t * 17 + k) * 2], s1 = wsu[F_SUB + (t * 17 + k) * 2 + 1];
      L = L + xla_log(u01(rbits(s0, s1, (unsigned)(b_ * 32 + d))));
      ws[F_LK + ((t * 32 + b_) * 17 + k) * 32 + d] = L;
    }
  }
}

// ---------------------------------------------------------------- sim: 3 barriers/step
__global__ void __launch_bounds__(1024) sim3_kernel(
    const float* __restrict__ state_init, const float* __restrict__ tseq,
    const float* __restrict__ gW1, const float* __restrict__ gb1,
    const float* __restrict__ gW2, const float* __restrict__ gb2,
    const float* __restrict__ gW3, const float* __restrict__ gb3,
    const float* __restrict__ ws, float* __restrict__ out) {
  const int b = blockIdx.x;
  const int tid = threadIdx.x;

  __shared__ float sW1[33 * 64], sB1[64], sW2[64 * 64], sB2[64], sW3[64 * 32], sB3[32];
  __shared__ float sTseq[64];
  __shared__ float sX[32], sK1[32], sA[32], sMb[32], sDrift[32], sDs[32];
  __shared__ float sH1[64], sH2[64];
  __shared__ float sTilt[32 * 65];
  __shared__ float sCond[512];

  for (int i = tid; i < 33 * 64; i += 1024) sW1[i] = gW1[i];
  for (int i = tid; i < 64 * 64; i += 1024) sW2[i] = gW2[i];
  for (int i = tid; i < 64 * 32; i += 1024) sW3[i] = gW3[i];
  if (tid < 64) { sB1[tid] = gb1[tid]; sB2[tid] = gb2[tid]; sTseq[tid] = tseq[tid]; }
  if (tid < 32) {
    sB3[tid] = gb3[tid];
    sDs[tid] = ws[F_DS + tid];
    float X0 = state_init[b * 32 + tid];
    sX[tid] = X0;
    float A = ws[F_A + tid], Bv = ws[F_B + tid];
    sA[tid] = A;
    float K1 = (2.0f * A) * X0 + Bv;
    sK1[tid] = K1;
    sMb[tid] = xla_exp((-(K1 * K1)) / (4.0f * A));
  }

  // prefetch step 0
  float cSc0, cSc1, cSc2, cQd0, cQd1, cQd2, cRp2[4], cSq[4], cU2[4];
  {
    int tb = b;
    cSc0 = ws[F_SCALED + tb * 2048 + tid];
    cQd0 = ws[F_QUAD + tb * 2048 + tid];
    cSc1 = (tid < 960) ? ws[F_SCALED + tb * 2048 + 960 + tid] : 0.0f;
    cQd1 = (tid < 960) ? ws[F_QUAD + tb * 2048 + 960 + tid] : 0.0f;
    cSc2 = (tid < 128) ? ws[F_SCALED + tb * 2048 + 1920 + tid] : 0.0f;
    cQd2 = (tid < 128) ? ws[F_QUAD + tb * 2048 + 1920 + tid] : 0.0f;
#pragma unroll
    for (int q = 0; q < 4; ++q) {
      cRp2[q] = ws[F_RP2 + tb * 4096 + tid + q * 1024];
      cSq[q]  = ws[F_SQ + tb * 4096 + tid + q * 1024];
      cU2[q]  = ws[F_U2 + tb * 4096 + tid + q * 1024];
    }
  }
  __syncthreads();

  const int lane = tid & 63;
  const int gbase = lane & 56;      // 8-lane group base within wave

  float past_t = sTseq[0];
  for (int ti = 0; ti < Tn; ++ti) {
    float t = sTseq[ti];
    float dt = t - past_t;

    // ---- issue next-step prefetch (waits land at end-of-step rotation)
    int tn = (ti < 63) ? ti + 1 : 63;
    float nSc0, nSc1, nSc2, nQd0, nQd1, nQd2, nRp2[4], nSq[4], nU2[4];
    float nA = 0.0f, nB = 0.0f;
    {
      int tb = tn * 32 + b;
      nSc0 = ws[F_SCALED + tb * 2048 + tid];
      nQd0 = ws[F_QUAD + tb * 2048 + tid];
      nSc1 = (tid < 960) ? ws[F_SCALED + tb * 2048 + 960 + tid] : 0.0f;
      nQd1 = (tid < 960) ? ws[F_QUAD + tb * 2048 + 960 + tid] : 0.0f;
      nSc2 = (tid < 128) ? ws[F_SCALED + tb * 2048 + 1920 + tid] : 0.0f;
      nQd2 = (tid < 128) ? ws[F_QUAD + tb * 2048 + 1920 + tid] : 0.0f;
#pragma unroll
      for (int q = 0; q < 4; ++q) {
        nRp2[q] = ws[F_RP2 + tb * 4096 + tid + q * 1024];
        nSq[q]  = ws[F_SQ + tb * 4096 + tid + q * 1024];
        nU2[q]  = ws[F_U2 + tb * 4096 + tid + q * 1024];
      }
      if (tid < 32) { nA = ws[F_A + tn * 32 + tid]; nB = ws[F_B + tn * 32 + tid]; }
    }

    // ---- P1: waves 0-14 tilt; wave 15 drift MLP (same-wave LDS)
    if (tid >= 960) {
      int l = tid - 960;
      float acc = 0.0f;
      acc = fmaf(t, sW1[l], acc);
      for (int k = 1; k < 33; ++k) acc = fmaf(sX[k - 1], sW1[k * 64 + l], acc);
      acc = acc + sB1[l];
      sH1[l] = xla_tanh(acc);
      float acc2 = 0.0f;
      for (int k = 0; k < 64; ++k) acc2 = fmaf(sH1[k], sW2[k * 64 + l], acc2);
      acc2 = acc2 + sB2[l];
      sH2[l] = xla_tanh(acc2);
      if (l < 32) {
        float a3 = 0.0f;
        for (int k = 0; k < 64; ++k) a3 = fmaf(sH2[k], sW3[k * 32 + l], a3);
        sDrift[l] = a3 + sB3[l];
      }
    } else {
      {
        int d = tid & 31;
        float lin = sK1[d] * cSc0;
        float lh = 80.0f * xla_tanh((cQd0 + lin) / 80.0f);
        float nh = 80.0f * xla_tanh((cQd0 - lin) / 80.0f);
        sTilt[d * 65 + (tid >> 5)] = xla_exp(lh) + xla_exp(nh);
      }
      {
        int e = tid + 960, d = e & 31;
        float lin = sK1[d] * cSc1;
        float lh = 80.0f * xla_tanh((cQd1 + lin) / 80.0f);
        float nh = 80.0f * xla_tanh((cQd1 - lin) / 80.0f);
        sTilt[d * 65 + (e >> 5)] = xla_exp(lh) + xla_exp(nh);
      }
      if (tid < 128) {
        int e = 1920 + tid, d = e & 31;
        float lin = sK1[d] * cSc2;
        float lh = 80.0f * xla_tanh((cQd2 + lin) / 80.0f);
        float nh = 80.0f * xla_tanh((cQd2 - lin) / 80.0f);
        sTilt[d * 65 + (e >> 5)] = xla_exp(lh) + xla_exp(nh);
      }
    }
    __syncthreads();   // B1

    // ---- P2: quantile clip (2 d's/wave) + candidates+select+cond (all waves)
    {
      // issue z loads early (consumed at end of phase)
      float zj[4];
#pragma unroll
      for (int q = 0; q < 4; ++q)
        zj[q] = ws[F_Z + (ti * 32 + b) * 512 + (tid >> 3) + q * 128];

      // quantile via 5 max-extractions (verified bit-exact in R5)
      int wv = tid >> 6;
      float vo0 = sTilt[wv * 65 + lane];
      float vo1 = sTilt[(wv + 16) * 65 + lane];
      float w0 = vo0, w1 = vo1;
      float s0_59 = 0.0f, s0_60 = 0.0f, s1_59 = 0.0f, s1_60 = 0.0f;
#pragma unroll
      for (int it = 0; it < 5; ++it) {
        float m0 = w0, m1 = w1;
#pragma unroll
        for (int j = 1; j < 64; j <<= 1) {
          m0 = fmaxf(m0, __shfl_xor(m0, j, 64));
          m1 = fmaxf(m1, __shfl_xor(m1, j, 64));
        }
        if (it == 3) { s0_60 = m0; s1_60 = m1; }
        if (it == 4) { s0_59 = m0; s1_59 = m1; }
        if (it < 4) {
          unsigned long long b0 = __ballot(w0 == m0);
          unsigned long long b1 = __ballot(w1 == m1);
          int l0 = __ffsll(b0) - 1;
          int l1 = __ffsll(b1) - 1;
          if (lane == l0) w0 = -1.0f;
          if (lane == l1) w1 = -1.0f;
        }
      }
      float qv = 0.95f * 63.0f;
      float hw = qv - 59.0f;
      float lw = 1.0f - hw;
      float tq0 = s0_59 * lw + s0_60 * hw;
      float tq1 = s1_59 * lw + s1_60 * hw;
      sTilt[wv * 65 + lane] = fminf(vo0, tq0);
      sTilt[(wv + 16) * 65 + lane] = fminf(vo1, tq1);

      // candidates: 8 attempts of jd live in 8 consecutive lanes -> in-wave select
#pragma unroll
      for (int q = 0; q < 4; ++q) {
        int tau = tid + q * 1024;
        int jd = tau >> 3, d = jd & 31;
        float A = sA[d], K1 = sK1[d];
        float K1sq = K1 * K1;
        float rp2 = cRp2[q];
        float den = fmaxf(1.0f - ((2.0f * A) * rp2) * SIG2F, 1e-6f);
        float Cv = xla_exp(((K1sq * rp2) * SIG2F) / (2.0f * den)) / cSq[q];
        float p = fminf(Cv / sMb[d], 1.0f);
        bool acc = (cU2[q] < p);
        unsigned long long m = __ballot(acc);
        unsigned grp = (unsigned)((m >> gbase) & 0xFFull);
        int first = (grp != 0u) ? (__ffs(grp) - 1) : 0;
        float got = __shfl(rp2, gbase + first, 64);
        float rp2sel = (grp != 0u) ? got : (0.1f * 0.1f);
        float t2 = (2.0f * rp2sel) * SIG2F;
        float K2 = A - 1.0f / t2;
        float K2s = (K2 < -1e-6f) ? K2 : -1e-6f;
        float mean = (-K1) / (2.0f * K2s);
        float var = (-1.0f) / (2.0f * K2s);
        float cond = mean + sqrtf(var) * zj[q];   // sqrtf: correctly rounded, continuous path
        if ((tid & 7) == 0) sCond[jd] = cond;
      }
    }
    __syncthreads();   // B2

    // ---- P3: poisson + masked sum + state update (tid<32)
    if (tid < 32) {
      int d = tid;
      float plk[17];
#pragma unroll
      for (int k = 0; k < 17; ++k) plk[k] = ws[F_LK + ((ti * 32 + b) * 17 + k) * 32 + d];
      float sum = 0.0f;
      for (int s = 0; s < 64; ++s) sum = sum + sTilt[d * 65 + s];
      float tilt = sum / 64.0f;
      float lam = (tilt * RATE1F) * dt;
      float negl = -lam;
      int n = 0;
#pragma unroll
      for (int k = 0; k < 17; ++k) n += (plk[k] > negl) ? 1 : 0;
      float soj = 0.0f;
      for (int j = 0; j < 16; ++j) {
        float cv = sCond[j * 32 + d];
        soj = soj + cv * ((j < n) ? 1.0f : 0.0f);
      }
      soj = 2.5f * xla_tanh(soj / 2.5f);
      float Xn = (sX[d] + sDrift[d] * dt) + sDs[d] * soj;
      sX[d] = Xn;
      out[ti * 1024 + b * 32 + d] = Xn;
      sA[d] = nA;
      float K1n = (2.0f * nA) * Xn + nB;
      sK1[d] = K1n;
      sMb[d] = xla_exp((-(K1n * K1n)) / (4.0f * nA));
    }
    __syncthreads();   // B3

    cSc0 = nSc0; cSc1 = nSc1; cSc2 = nSc2;
    cQd0 = nQd0; cQd1 = nQd1; cQd2 = nQd2;
#pragma unroll
    for (int q = 0; q < 4; ++q) { cRp2[q] = nRp2[q]; cSq[q] = nSq[q]; cU2[q] = nU2[q]; }
    past_t = t;
  }
}

// ---------------------------------------------------------------- launch
extern "C" void kernel_launch(void* const* d_in, const int* in_sizes, int n_in,
                              void* d_out, int out_size, void* d_ws, size_t ws_size,
                              hipStream_t stream) {
  const float* state_init = (const float*)d_in[0];
  const float* tseq       = (const float*)d_in[1];
  const float* dW1        = (const float*)d_in[2];
  const float* db1        = (const float*)d_in[3];
  const float* dW2        = (const float*)d_in[4];
  const float* db2        = (const float*)d_in[5];
  const float* dW3        = (const float*)d_in[6];
  const float* db3        = (const float*)d_in[7];
  const float* diff_log   = (const float*)d_in[8];
  const float* pW1        = (const float*)d_in[9];
  const float* pb1        = (const float*)d_in[10];
  const float* pW2        = (const float*)d_in[11];
  const float* pb2        = (const float*)d_in[12];
  const float* pW3        = (const float*)d_in[13];
  const float* pb3        = (const float*)d_in[14];
  float* ws = (float*)d_ws;
  unsigned* wsu = (unsigned*)d_ws;

  // ws_size >= F_END*4 (143MB) proven in R5 (fat path executed successfully).
  key_kernel<<<1, 64, 0, stream>>>(wsu);
  phi_kernel<<<64, 64, 0, stream>>>(tseq, pW1, pb1, pW2, pb2, pW3, pb3, diff_log, ws);
  stable2_kernel<<<dim3(836, 64), 256, 0, stream>>>(wsu, ws);
  sim3_kernel<<<32, 1024, 0, stream>>>(state_init, tseq, dW1, db1, dW2, db2,
                                       dW3, db3, ws, (float*)d_out);
}

// Round 7
// 694.125 us; speedup vs baseline: 1.9027x; 1.0624x over previous
//
#include <hip/hip_runtime.h>
#include <cstdint>
#include <math.h>

// XLA CPU (no fast-math) emits unfused mul/add for all HLO-level elementwise ops.
#pragma clang fp contract(off)

#define DEV __device__ __forceinline__

// ---------------------------------------------------------------- threefry2x32
struct U2 { unsigned a, b; };

DEV unsigned rotl32(unsigned v, int d) { return (v << d) | (v >> (32 - d)); }

DEV U2 tf2(unsigned k0, unsigned k1, unsigned x0, unsigned x1) {
  unsigned ks2 = k0 ^ k1 ^ 0x1BD11BDAu;
  x0 += k0; x1 += k1;
#define TFR(r) { x0 += x1; x1 = rotl32(x1, r); x1 ^= x0; }
  TFR(13) TFR(15) TFR(26) TFR(6)
  x0 += k1; x1 += ks2 + 1u;
  TFR(17) TFR(29) TFR(16) TFR(24)
  x0 += ks2; x1 += k0 + 2u;
  TFR(13) TFR(15) TFR(26) TFR(6)
  x0 += k0; x1 += k1 + 3u;
  TFR(17) TFR(29) TFR(16) TFR(24)
  x0 += k1; x1 += ks2 + 4u;
  TFR(13) TFR(15) TFR(26) TFR(6)
  x0 += ks2; x1 += k0 + 5u;
#undef TFR
  U2 r; r.a = x0; r.b = x1; return r;
}

DEV unsigned rbits(unsigned k0, unsigned k1, unsigned idx) {
  U2 o = tf2(k0, k1, 0u, idx);
  return o.a ^ o.b;
}

DEV float u01(unsigned bits) {
  return __uint_as_float((bits >> 9) | 0x3F800000u) - 1.0f;
}

// ---------------------------------------------------------------- XLA CPU math
DEV float xla_exp(float xi) {
  float x = fminf(fmaxf(xi, -88.3762626647949f), 88.3762626647950f);
  float fx = floorf(x * 1.44269504088896341f + 0.5f);
  float tmp = 0.693359375f * fx;
  float z = -2.12194440e-4f * fx;
  x = x - tmp;
  x = x - z;
  z = x * x;
  float y = 1.9875691500e-4f * x + 1.3981999507e-3f;
  y = y * x + 8.3334519073e-3f;
  y = y * x + 4.1665795894e-2f;
  y = y * x + 1.6666665459e-1f;
  y = y * x + 5.0000001201e-1f;
  y = y * z + x;
  y = y + 1.0f;
  int n = (int)fx;
  float two_n = __uint_as_float((unsigned)(n + 127) << 23);
  return fmaxf(y * two_n, xi);
}

DEV float xla_log(float xi) {
  float xc = fmaxf(xi, 1.17549435082228751e-38f);
  unsigned bits = __float_as_uint(xc);
  float e = (float)((int)(bits >> 23) - 126);
  float m = __uint_as_float((bits & 0x007FFFFFu) | 0x3F000000u);
  bool msk = m < 0.707106781186547524f;
  float tmp = msk ? m : 0.0f;
  float em  = msk ? 1.0f : 0.0f;
  m = m - 1.0f;
  e = e - em;
  m = m + tmp;
  float z  = m * m;
  float x3 = z * m;
  float y0 = 7.0376836292e-2f  * m + -1.1514610310e-1f;
  float y1 = -1.2420140846e-1f * m + 1.4249322787e-1f;
  float y2 = 2.0000714765e-1f  * m + -2.4999993993e-1f;
  y0 = y0 * m + 1.1676998740e-1f;
  y1 = y1 * m + -1.6668057665e-1f;
  y2 = y2 * m + 3.3333331174e-1f;
  y0 = y0 * x3 + y1;
  y0 = y0 * x3 + y2;
  y0 = y0 * x3;
  y0 = -2.12194440e-4f * e + y0;
  y0 = y0 - 0.5f * z;
  float r = m + y0;
  r = 0.693359375f * e + r;
  if (!(xi > 0.0f)) r = (xi == 0.0f) ? -__builtin_inff() : __builtin_nanf("");
  if (xi == __builtin_inff()) r = __builtin_inff();
  return r;
}

DEV float xla_tanh(float x) {
  float xc = fminf(fmaxf(x, -9.0f), 9.0f);
  float x2 = xc * xc;
  float p = x2 * -2.76076847742355e-16f + 2.00018790482477e-13f;
  p = p * x2 + -8.60467152213735e-11f;
  p = p * x2 + 5.12229709037114e-08f;
  p = p * x2 + 1.48572235717979e-05f;
  p = p * x2 + 6.37261928875436e-04f;
  p = p * x2 + 4.89352455891786e-03f;
  p = xc * p;
  float q = x2 * 1.19825839466702e-06f + 1.18534705686654e-04f;
  q = q * x2 + 2.26843463243900e-03f;
  q = q * x2 + 4.89352518554385e-03f;
  float r = p / q;
  return (fabsf(x) < 0.0004f) ? x : r;
}

DEV float sqrt_cr(float x) { return (float)sqrt((double)x); }

DEV float xla_log1p(float x) {
  float fl = xla_log(x + 1.0f);
  float fs = ((-0.5f) * x + 1.0f) * x;
  return (fabsf(x) < 1e-4f) ? fs : fl;
}

DEV float softplus_ref(float x) {
  float amax = fmaxf(x, 0.0f);
  return amax + xla_log1p(xla_exp(-fabsf(x)));
}

DEV float xla_erfinv(float x) {
  float w = -xla_log1p(-(x * x));
  bool lt = w < 5.0f;
  float wa = lt ? (w - 2.5f) : (sqrt_cr(w) - 3.0f);
  float p;
  if (lt) {
    p = 2.81022636e-08f;
    p = p * wa + 3.43273939e-07f;
    p = p * wa + -3.5233877e-06f;
    p = p * wa + -4.39150654e-06f;
    p = p * wa + 0.00021858087f;
    p = p * wa + -0.00125372503f;
    p = p * wa + -0.00417768164f;
    p = p * wa + 0.246640727f;
    p = p * wa + 1.50140941f;
  } else {
    p = -0.000200214257f;
    p = p * wa + 0.000100950558f;
    p = p * wa + 0.00134934322f;
    p = p * wa + -0.00367342844f;
    p = p * wa + 0.00573950773f;
    p = p * wa + -0.0076224613f;
    p = p * wa + 0.00943887047f;
    p = p * wa + 1.00167406f;
    p = p * wa + 2.83297682f;
  }
  return p * x;
}

// ---------------------------------------------------------------- custom f64 pow
// x^E for x in (2^-24, 1], E = -(float)(1/1.2). ~2-3 f64 ulp; validated R6.
DEV float powm_fast(float xf) {
  const double E = (double)((float)(-1.0 / 1.2));
  double x = (double)xf;
  long long bits = __double_as_longlong(x);
  int k = (int)((bits >> 52) & 0x7FFLL) - 1023;
  double m = __longlong_as_double((bits & 0x000FFFFFFFFFFFFFLL) | 0x3FF0000000000000LL);
  if (m > 1.4142135623730951) { m = m * 0.5; k = k + 1; }
  double z = (m - 1.0) / (m + 1.0);
  double z2 = z * z;
  double pl = 0.11541560327111707;
  pl = fma(pl, z2, 0.12545174268599682);
  pl = fma(pl, z2, 0.13739952770371080);
  pl = fma(pl, z2, 0.15186263588304878);
  pl = fma(pl, z2, 0.16972882833987805);
  pl = fma(pl, z2, 0.19235933878519512);
  pl = fma(pl, z2, 0.22195308321368668);
  pl = fma(pl, z2, 0.26230818925253880);
  pl = fma(pl, z2, 0.32059889797532520);
  pl = fma(pl, z2, 0.41219858311113240);
  pl = fma(pl, z2, 0.57707801635558537);
  pl = fma(pl, z2, 0.96179669392597556);
  pl = fma(pl, z2, 2.88539008177792681);
  double t = (double)k + z * pl;
  double yh = E * t;
  double yl = fma(E, t, -yh);
  double fn = floor(yh + 0.5);
  double f = yh - fn;
  double w = f * 0.69314718055994531;
  double ew = 1.6059043836821613e-10;
  ew = fma(ew, w, 2.0876756987868099e-9);
  ew = fma(ew, w, 2.5052108385441719e-8);
  ew = fma(ew, w, 2.7557319223985893e-7);
  ew = fma(ew, w, 2.7557319223985888e-6);
  ew = fma(ew, w, 2.4801587301587302e-5);
  ew = fma(ew, w, 1.9841269841269841e-4);
  ew = fma(ew, w, 1.3888888888888889e-3);
  ew = fma(ew, w, 8.3333333333333332e-3);
  ew = fma(ew, w, 4.1666666666666664e-2);
  ew = fma(ew, w, 0.16666666666666666);
  ew = fma(ew, w, 0.5);
  ew = fma(ew, w, 1.0);
  ew = fma(ew, w, 1.0);
  int n = (int)fn;
  double r = ew * __longlong_as_double((long long)(n + 1023) << 52);
  r = fma(r, yl * 0.69314718055994531, r);
  return (float)r;
}

// ---------------------------------------------------------------- constants
#define SIG2F  0.0025000000000000005f
#define RATE1F 13.207443270509278f
#define LO_N  -0.99999994039535522f
#define SQRT2F 1.4142135623730951f
#define Tn 64

// ---------------------------------------------------------------- ws layout (floats)
#define F_A      0          // 2048
#define F_B      2048       // 2048
#define F_DS     4096       // 32
#define F_KEYS   4128       // 512 u
#define F_KA     4640       // 1024 u
#define F_KP     5664       // 1024 u
#define F_SUB    6688       // 2176 u
#define F_SCALED 16384      // 4194304
#define F_QUAD   4210688    // 4194304
#define F_RP2    8404992    // 8388608
#define F_SQ     16793600   // 8388608
#define F_U2     25182208   // 8388608
#define F_Z      33570816   // 1048576
#define F_LK     34619392   // 1114112
#define F_END    35733504   // 143 MB — proven available (R5)

// ---------------------------------------------------------------- phi + keys
// 64 blocks x 64 threads; block t does phi for step t; block 0 also builds key tables.
__global__ void __launch_bounds__(64) phikey_kernel(
    const float* __restrict__ tseq,
    const float* __restrict__ pW1, const float* __restrict__ pb1,
    const float* __restrict__ pW2, const float* __restrict__ pb2,
    const float* __restrict__ pW3, const float* __restrict__ pb3,
    const float* __restrict__ diff_log, float* __restrict__ ws) {
  unsigned* wsu = (unsigned*)ws;
  __shared__ float h1[64], h2[64];
  __shared__ unsigned lk[64][2];
  int t = blockIdx.x, w = threadIdx.x;

  if (t == 0) {
    if (w == 0) {
      unsigned k0 = 0u, k1 = 42u;   // jax.random.key(42)
      for (int i = 0; i < 64; ++i) {
        lk[i][0] = k0; lk[i][1] = k1;
        U2 c0 = tf2(k0, k1, 0u, 0u);
        k0 = c0.a; k1 = c0.b;
      }
    }
    __syncthreads();
    unsigned k0 = lk[w][0], k1 = lk[w][1];
    U2 c1 = tf2(k0, k1, 0u, 1u);  // k_stab
    U2 c2 = tf2(k0, k1, 0u, 2u);  // k_pois
    U2 c3 = tf2(k0, k1, 0u, 3u);  // k_rej
    U2 c4 = tf2(k0, k1, 0u, 4u);  // k_gauss
    wsu[F_KEYS + w * 8 + 0] = c1.a; wsu[F_KEYS + w * 8 + 1] = c1.b;
    wsu[F_KEYS + w * 8 + 2] = c2.a; wsu[F_KEYS + w * 8 + 3] = c2.b;
    wsu[F_KEYS + w * 8 + 4] = c3.a; wsu[F_KEYS + w * 8 + 5] = c3.b;
    wsu[F_KEYS + w * 8 + 6] = c4.a; wsu[F_KEYS + w * 8 + 7] = c4.b;
    unsigned a0 = c3.a, a1 = c3.b;
    for (int a = 0; a < 8; ++a) {
      U2 kp = tf2(a0, a1, 0u, 1u);
      U2 ka = tf2(a0, a1, 0u, 2u);
      U2 nx = tf2(a0, a1, 0u, 0u);
      wsu[F_KP + (w * 8 + a) * 2 + 0] = kp.a; wsu[F_KP + (w * 8 + a) * 2 + 1] = kp.b;
      wsu[F_KA + (w * 8 + a) * 2 + 0] = ka.a; wsu[F_KA + (w * 8 + a) * 2 + 1] = ka.b;
      a0 = nx.a; a1 = nx.b;
    }
    unsigned r0 = c2.a, r1 = c2.b;
    for (int k = 0; k < 17; ++k) {
      U2 sub = tf2(r0, r1, 0u, 1u);
      U2 nx  = tf2(r0, r1, 0u, 0u);
      wsu[F_SUB + (w * 17 + k) * 2 + 0] = sub.a; wsu[F_SUB + (w * 17 + k) * 2 + 1] = sub.b;
      r0 = nx.a; r1 = nx.b;
    }
    __syncthreads();
  }

  float tv = tseq[t];
  h1[w] = xla_tanh(tv * pW1[w] + pb1[w]);
  __syncthreads();
  float acc = 0.0f;
  for (int k = 0; k < 64; ++k) acc = fmaf(h1[k], pW2[k * 64 + w], acc);
  acc = acc + pb2[w];
  h2[w] = xla_tanh(acc);
  __syncthreads();
  acc = 0.0f;
  for (int k = 0; k < 64; ++k) acc = fmaf(h2[k], pW3[k * 64 + w], acc);
  acc = acc + pb3[w];
  if (w < 32) ws[F_A + t * 32 + w] = -softplus_ref(acc);
  else        ws[F_B + t * 32 + (w - 32)] = acc;
  if (t == 0 && w < 32) ws[F_DS + w] = softplus_ref(diff_log[w]);
}

// ---------------------------------------------------------------- stable precompute
// grid (836, 64): 836*256 = 214016 units per slab t = blockIdx.y
__global__ void __launch_bounds__(256) stable2_kernel(const unsigned* __restrict__ wsu,
                                                      float* __restrict__ ws) {
  int t = blockIdx.y;
  int u = blockIdx.x * 256 + threadIdx.x;
  if (u < 65536) {
    int b_ = u >> 11, e = u & 2047, d = e & 31;
    unsigned k0 = wsu[F_KEYS + t * 8 + 0], k1 = wsu[F_KEYS + t * 8 + 1];
    float uu = u01(rbits(k0, k1, (unsigned)(b_ * 2048 + e)));
    float raw = 0.1f * powm_fast(1.0f - uu);
    float scaled = ws[F_DS + d] * raw;
    float A = ws[F_A + t * 32 + d];
    ws[F_SCALED + t * 65536 + u] = scaled;
    ws[F_QUAD   + t * 65536 + u] = A * (scaled * scaled);
  } else if (u < 196608) {
    int i = u - 65536;
    int b_ = i >> 12, jd = (i >> 3) & 511, a = i & 7, d = jd & 31;
    unsigned p0 = wsu[F_KP + (t * 8 + a) * 2], p1 = wsu[F_KP + (t * 8 + a) * 2 + 1];
    float rp = 0.1f * powm_fast(1.0f - u01(rbits(p0, p1, (unsigned)(b_ * 512 + jd))));
    float rp2 = rp * rp;
    float A = ws[F_A + t * 32 + d];
    float den = fmaxf(1.0f - ((2.0f * A) * rp2) * SIG2F, 1e-6f);
    unsigned a0 = wsu[F_KA + (t * 8 + a) * 2], a1 = wsu[F_KA + (t * 8 + a) * 2 + 1];
    ws[F_RP2 + t * 131072 + i] = rp2;
    ws[F_SQ  + t * 131072 + i] = sqrt_cr(den);   // f64 sqrt: feeds accept decision
    ws[F_U2  + t * 131072 + i] = u01(rbits(a0, a1, (unsigned)(b_ * 512 + jd)));
  } else if (u < 212992) {
    int i = u - 196608;
    int b_ = i >> 9, jd = i & 511;
    unsigned g0 = wsu[F_KEYS + t * 8 + 6], g1 = wsu[F_KEYS + t * 8 + 7];
    float fz = u01(rbits(g0, g1, (unsigned)(b_ * 512 + jd)));
    float un = fmaxf(LO_N, fz * 2.0f + LO_N);
    ws[F_Z + t * 16384 + i] = SQRT2F * xla_erfinv(un);
  } else {
    int i = u - 212992;
    int b_ = i >> 5, d = i & 31;
    float L = 0.0f;
    for (int k = 0; k < 17; ++k) {
      unsigned s0 = wsu[F_SUB + (t * 17 + k) * 2], s1 = wsu[F_SUB + (t * 17 + k) * 2 + 1];
      L = L + xla_log(u01(rbits(s0, s1, (unsigned)(b_ * 32 + d))));
      ws[F_LK + ((t * 32 + b_) * 17 + k) * 32 + d] = L;
    }
  }
}

// ---------------------------------------------------------------- sim: 3 barriers/step
__global__ void __launch_bounds__(1024) sim4_kernel(
    const float* __restrict__ state_init, const float* __restrict__ tseq,
    const float* __restrict__ gW1, const float* __restrict__ gb1,
    const float* __restrict__ gW2, const float* __restrict__ gb2,
    const float* __restrict__ gW3, const float* __restrict__ gb3,
    const float* __restrict__ ws, float* __restrict__ out) {
  const int b = blockIdx.x;
  const int tid = threadIdx.x;

  __shared__ float sW1[33 * 64], sB1[64], sW2[64 * 64], sB2[64], sW3[64 * 32], sB3[32];
  __shared__ float sTseq[64];
  __shared__ float sX[32], sK1[32], sA[32], sMb[32], sDrift[32], sDs[32];
  __shared__ float sH1[64], sH2[64];
  __shared__ float sTilt[32 * 65];
  __shared__ float sCond[512];

  for (int i = tid; i < 33 * 64; i += 1024) sW1[i] = gW1[i];
  for (int i = tid; i < 64 * 64; i += 1024) sW2[i] = gW2[i];
  for (int i = tid; i < 64 * 32; i += 1024) sW3[i] = gW3[i];
  if (tid < 64) { sB1[tid] = gb1[tid]; sB2[tid] = gb2[tid]; sTseq[tid] = tseq[tid]; }
  if (tid < 32) {
    sB3[tid] = gb3[tid];
    sDs[tid] = ws[F_DS + tid];
    float X0 = state_init[b * 32 + tid];
    sX[tid] = X0;
    float A = ws[F_A + tid], Bv = ws[F_B + tid];
    sA[tid] = A;
    float K1 = (2.0f * A) * X0 + Bv;
    sK1[tid] = K1;
    sMb[tid] = xla_exp((-(K1 * K1)) / (4.0f * A));
  }

  // prefetch step 0
  float cSc0, cSc1, cSc2, cQd0, cQd1, cQd2, cRp2[4], cSq[4], cU2[4];
  {
    int tb = b;
    cSc0 = ws[F_SCALED + tb * 2048 + tid];
    cQd0 = ws[F_QUAD + tb * 2048 + tid];
    cSc1 = (tid < 960) ? ws[F_SCALED + tb * 2048 + 960 + tid] : 0.0f;
    cQd1 = (tid < 960) ? ws[F_QUAD + tb * 2048 + 960 + tid] : 0.0f;
    cSc2 = (tid < 128) ? ws[F_SCALED + tb * 2048 + 1920 + tid] : 0.0f;
    cQd2 = (tid < 128) ? ws[F_QUAD + tb * 2048 + 1920 + tid] : 0.0f;
#pragma unroll
    for (int q = 0; q < 4; ++q) {
      cRp2[q] = ws[F_RP2 + tb * 4096 + tid + q * 1024];
      cSq[q]  = ws[F_SQ + tb * 4096 + tid + q * 1024];
      cU2[q]  = ws[F_U2 + tb * 4096 + tid + q * 1024];
    }
  }
  __syncthreads();

  const int lane = tid & 63;
  const int gbase = lane & 56;          // 8-lane group base within wave
  const int jdm = (tid >> 3) + (tid & 3) * 128;   // my cond assignment

  float past_t = sTseq[0];
  for (int ti = 0; ti < Tn; ++ti) {
    float t = sTseq[ti];
    float dt = t - past_t;

    // ---- step-top prefetches: this step's plk + z, next step's slab
    float plk[17];
    if (tid < 32) {
#pragma unroll
      for (int k = 0; k < 17; ++k) plk[k] = ws[F_LK + ((ti * 32 + b) * 17 + k) * 32 + tid];
    }
    float zm = ws[F_Z + (ti * 32 + b) * 512 + jdm];

    int tn = (ti < 63) ? ti + 1 : 63;
    float nSc0, nSc1, nSc2, nQd0, nQd1, nQd2, nRp2[4], nSq[4], nU2[4];
    float nA = 0.0f, nB = 0.0f;
    {
      int tb = tn * 32 + b;
      nSc0 = ws[F_SCALED + tb * 2048 + tid];
      nQd0 = ws[F_QUAD + tb * 2048 + tid];
      nSc1 = (tid < 960) ? ws[F_SCALED + tb * 2048 + 960 + tid] : 0.0f;
      nQd1 = (tid < 960) ? ws[F_QUAD + tb * 2048 + 960 + tid] : 0.0f;
      nSc2 = (tid < 128) ? ws[F_SCALED + tb * 2048 + 1920 + tid] : 0.0f;
      nQd2 = (tid < 128) ? ws[F_QUAD + tb * 2048 + 1920 + tid] : 0.0f;
#pragma unroll
      for (int q = 0; q < 4; ++q) {
        nRp2[q] = ws[F_RP2 + tb * 4096 + tid + q * 1024];
        nSq[q]  = ws[F_SQ + tb * 4096 + tid + q * 1024];
        nU2[q]  = ws[F_U2 + tb * 4096 + tid + q * 1024];
      }
      if (tid < 32) { nA = ws[F_A + tn * 32 + tid]; nB = ws[F_B + tn * 32 + tid]; }
    }

    // ---- P1: waves 0-14 tilt; wave 15 drift MLP (same-wave LDS)
    if (tid >= 960) {
      int l = tid - 960;
      float acc = 0.0f;
      acc = fmaf(t, sW1[l], acc);
      for (int k = 1; k < 33; ++k) acc = fmaf(sX[k - 1], sW1[k * 64 + l], acc);
      acc = acc + sB1[l];
      sH1[l] = xla_tanh(acc);
      float acc2 = 0.0f;
      for (int k = 0; k < 64; ++k) acc2 = fmaf(sH1[k], sW2[k * 64 + l], acc2);
      acc2 = acc2 + sB2[l];
      sH2[l] = xla_tanh(acc2);
      if (l < 32) {
        float a3 = 0.0f;
        for (int k = 0; k < 64; ++k) a3 = fmaf(sH2[k], sW3[k * 32 + l], a3);
        sDrift[l] = a3 + sB3[l];
      }
    } else {
      // d is identical for all three tasks (960 and 1920 are multiples of 32)
      int d = tid & 31;
      float K1 = sK1[d];
      {
        float lin = K1 * cSc0;
        float lh = 80.0f * xla_tanh((cQd0 + lin) / 80.0f);
        float nh = 80.0f * xla_tanh((cQd0 - lin) / 80.0f);
        sTilt[d * 65 + (tid >> 5)] = xla_exp(lh) + xla_exp(nh);
      }
      {
        float lin = K1 * cSc1;
        float lh = 80.0f * xla_tanh((cQd1 + lin) / 80.0f);
        float nh = 80.0f * xla_tanh((cQd1 - lin) / 80.0f);
        sTilt[d * 65 + (tid >> 5) + 30] = xla_exp(lh) + xla_exp(nh);
      }
      if (tid < 128) {
        float lin = K1 * cSc2;
        float lh = 80.0f * xla_tanh((cQd2 + lin) / 80.0f);
        float nh = 80.0f * xla_tanh((cQd2 - lin) / 80.0f);
        sTilt[d * 65 + (tid >> 5) + 60] = xla_exp(lh) + xla_exp(nh);
      }
    }
    __syncthreads();   // B1

    // ---- P2: quantile clip (2 d's/wave) + candidates + in-wave select + 1 cond/lane
    {
      // quantile via 5 max-extractions
      int wv = tid >> 6;
      float vo0 = sTilt[wv * 65 + lane];
      float vo1 = sTilt[(wv + 16) * 65 + lane];
      float w0 = vo0, w1 = vo1;
      float s0_59 = 0.0f, s0_60 = 0.0f, s1_59 = 0.0f, s1_60 = 0.0f;
#pragma unroll
      for (int it = 0; it < 5; ++it) {
        float m0 = w0, m1 = w1;
#pragma unroll
        for (int j = 1; j < 64; j <<= 1) {
          m0 = fmaxf(m0, __shfl_xor(m0, j, 64));
          m1 = fmaxf(m1, __shfl_xor(m1, j, 64));
        }
        if (it == 3) { s0_60 = m0; s1_60 = m1; }
        if (it == 4) { s0_59 = m0; s1_59 = m1; }
        if (it < 4) {
          unsigned long long b0 = __ballot(w0 == m0);
          unsigned long long b1 = __ballot(w1 == m1);
          int l0 = __ffsll(b0) - 1;
          int l1 = __ffsll(b1) - 1;
          if (lane == l0) w0 = -1.0f;
          if (lane == l1) w1 = -1.0f;
        }
      }
      float qv = 0.95f * 63.0f;
      float hw = qv - 59.0f;
      float lw = 1.0f - hw;
      float tq0 = s0_59 * lw + s0_60 * hw;
      float tq1 = s1_59 * lw + s1_60 * hw;
      sTilt[wv * 65 + lane] = fminf(vo0, tq0);
      sTilt[(wv + 16) * 65 + lane] = fminf(vo1, tq1);

      // candidates: d identical for all 4 q (q*128 ≡ 0 mod 32)
      int d = (tid >> 3) & 31;
      float A = sA[d], K1 = sK1[d], Mb = sMb[d];
      float K1sq = K1 * K1;
      float rsel[4];
#pragma unroll
      for (int q = 0; q < 4; ++q) {
        float rp2 = cRp2[q];
        float den = fmaxf(1.0f - ((2.0f * A) * rp2) * SIG2F, 1e-6f);
        float Cv = xla_exp(((K1sq * rp2) * SIG2F) / (2.0f * den)) / cSq[q];
        float p = fminf(Cv / Mb, 1.0f);
        bool acc = (cU2[q] < p);
        unsigned long long m = __ballot(acc);
        unsigned grp = (unsigned)((m >> gbase) & 0xFFull);
        int first = (grp != 0u) ? (__ffs(grp) - 1) : 0;
        float got = __shfl(rp2, gbase + first, 64);
        rsel[q] = (grp != 0u) ? got : (0.1f * 0.1f);
      }
      // one cond per lane: myq = tid&3 (lanes 4-7 duplicate 0-3, store-masked)
      int myq = tid & 3;
      float rp2m = rsel[0];
      rp2m = (myq == 1) ? rsel[1] : rp2m;
      rp2m = (myq == 2) ? rsel[2] : rp2m;
      rp2m = (myq == 3) ? rsel[3] : rp2m;
      float t2 = (2.0f * rp2m) * SIG2F;
      float K2 = A - 1.0f / t2;
      float K2s = (K2 < -1e-6f) ? K2 : -1e-6f;
      float mean = (-K1) / (2.0f * K2s);
      float var = (-1.0f) / (2.0f * K2s);
      float cond = mean + sqrtf(var) * zm;
      if ((tid & 7) < 4) sCond[jdm] = cond;
    }
    __syncthreads();   // B2

    // ---- P3: poisson (prefetched plk) + masked in-order sum + state update
    if (tid < 32) {
      int d = tid;
      float sum = 0.0f;
      for (int s = 0; s < 64; ++s) sum = sum + sTilt[d * 65 + s];
      float tilt = sum / 64.0f;
      float lam = (tilt * RATE1F) * dt;
      float negl = -lam;
      int n = 0;
#pragma unroll
      for (int k = 0; k < 17; ++k) n += (plk[k] > negl) ? 1 : 0;
      float soj = 0.0f;
      for (int j = 0; j < 16; ++j) {
        float cv = sCond[j * 32 + d];
        soj = soj + cv * ((j < n) ? 1.0f : 0.0f);
      }
      soj = 2.5f * xla_tanh(soj / 2.5f);
      float Xn = (sX[d] + sDrift[d] * dt) + sDs[d] * soj;
      sX[d] = Xn;
      out[ti * 1024 + b * 32 + d] = Xn;
      sA[d] = nA;
      float K1n = (2.0f * nA) * Xn + nB;
      sK1[d] = K1n;
      sMb[d] = xla_exp((-(K1n * K1n)) / (4.0f * nA));
    }
    __syncthreads();   // B3

    cSc0 = nSc0; cSc1 = nSc1; cSc2 = nSc2;
    cQd0 = nQd0; cQd1 = nQd1; cQd2 = nQd2;
#pragma unroll
    for (int q = 0; q < 4; ++q) { cRp2[q] = nRp2[q]; cSq[q] = nSq[q]; cU2[q] = nU2[q]; }
    past_t = t;
  }
}

// ---------------------------------------------------------------- launch
extern "C" void kernel_launch(void* const* d_in, const int* in_sizes, int n_in,
                              void* d_out, int out_size, void* d_ws, size_t ws_size,
                              hipStream_t stream) {
  const float* state_init = (const float*)d_in[0];
  const float* tseq       = (const float*)d_in[1];
  const float* dW1        = (const float*)d_in[2];
  const float* db1        = (const float*)d_in[3];
  const float* dW2        = (const float*)d_in[4];
  const float* db2        = (const float*)d_in[5];
  const float* dW3        = (const float*)d_in[6];
  const float* db3        = (const float*)d_in[7];
  const float* diff_log   = (const float*)d_in[8];
  const float* pW1        = (const float*)d_in[9];
  const float* pb1        = (const float*)d_in[10];
  const float* pW2        = (const float*)d_in[11];
  const float* pb2        = (const float*)d_in[12];
  const float* pW3        = (const float*)d_in[13];
  const float* pb3        = (const float*)d_in[14];
  float* ws = (float*)d_ws;
  unsigned* wsu = (unsigned*)d_ws;

  phikey_kernel<<<64, 64, 0, stream>>>(tseq, pW1, pb1, pW2, pb2, pW3, pb3, diff_log, ws);
  stable2_kernel<<<dim3(836, 64), 256, 0, stream>>>(wsu, ws);
  sim4_kernel<<<32, 1024, 0, stream>>>(state_init, tseq, dW1, db1, dW2, db2,
                                       dW3, db3, ws, (float*)d_out);
}